// Round 14
// baseline (14772.897 us; speedup 1.0000x reference)
//
#include <hip/hip_runtime.h>

typedef unsigned short u16;
typedef unsigned int u32;
typedef __attribute__((ext_vector_type(8))) short s16x8;
typedef __attribute__((ext_vector_type(4))) float f32x4;

#define MFMA_BF16 __builtin_amdgcn_mfma_f32_16x16x32_bf16
#define SCOPE_AGT __HIP_MEMORY_SCOPE_AGENT

__device__ __forceinline__ float sigf(float x) { return 1.f / (1.f + __expf(-x)); }
__device__ __forceinline__ float tanh_fast(float x) {
    float e = __expf(2.f * x);
    return 1.f - 2.f / (e + 1.f);
}
__device__ __forceinline__ u16 bf16_rn(float x) {
    u32 u = __float_as_uint(x);
    u += 0x7FFFu + ((u >> 16) & 1u);
    return (u16)(u >> 16);
}
__device__ __forceinline__ void split_store(float v, u16* __restrict__ ph,
                                            u16* __restrict__ pl, size_t off) {
    u16 h = bf16_rn(v);
    float hf = __uint_as_float(((u32)h) << 16);
    ph[off] = h;
    pl[off] = bf16_rn(v - hf);
}
__device__ __forceinline__ void mma3(f32x4& acc, s16x8 ah, s16x8 al, s16x8 wh, s16x8 wl) {
    acc = MFMA_BF16(ah, wh, acc, 0, 0, 0);
    acc = MFMA_BF16(al, wh, acc, 0, 0, 0);
    acc = MFMA_BF16(ah, wl, acc, 0, 0, 0);
}
__device__ __forceinline__ void gll16(const u16* g, u16* l) {
    __builtin_amdgcn_global_load_lds(
        (const __attribute__((address_space(1))) u32*)g,
        (__attribute__((address_space(3))) u32*)l, 16, 0, 0);
}

// ---------------- weight prep: fragment blocks, plane-separated ----------------
__global__ __launch_bounds__(256) void prep_w(const float* __restrict__ S1, int ld1, int K1,
                                              const float* __restrict__ S2, int ld2,
                                              u16* __restrict__ out, int NF) {
    int idx = blockIdx.x * 256 + threadIdx.x;
    int l = idx & 63;
    int u = idx >> 6;
    int f = u % NF;
    int s = u / NF;
    int n = f * 16 + (l & 15);
    int kb = s * 32 + ((l >> 4) << 3);
    u16* o = out + (size_t)u * 1024 + l * 8;
#pragma unroll
    for (int j = 0; j < 8; ++j) {
        int k = kb + j;
        float v = (k < K1) ? S1[(size_t)n * ld1 + k] : S2[(size_t)n * ld2 + (k - K1)];
        u16 h = bf16_rn(v);
        float hf = __uint_as_float(((u32)h) << 16);
        o[j] = h;
        o[512 + j] = bf16_rn(v - hf);
    }
}

__global__ __launch_bounds__(256) void prep_act(const float* __restrict__ in,
                                                u16* __restrict__ hi, u16* __restrict__ lo,
                                                int n4) {
    int i = blockIdx.x * 256 + threadIdx.x;
    if (i >= n4) return;
    float4 v = ((const float4*)in)[i];
    float vv[4] = {v.x, v.y, v.z, v.w};
    u16 h[4], lw[4];
#pragma unroll
    for (int j = 0; j < 4; ++j) {
        h[j] = bf16_rn(vv[j]);
        float hf = __uint_as_float(((u32)h[j]) << 16);
        lw[j] = bf16_rn(vv[j] - hf);
    }
    ((ushort4*)hi)[i] = make_ushort4(h[0], h[1], h[2], h[3]);
    ((ushort4*)lo)[i] = make_ushort4(lw[0], lw[1], lw[2], lw[3]);
}

// ---------------- XCD-local barrier: relaxed flags + L1-only invalidate ----------------
__device__ __forceinline__ void barx(u32* __restrict__ flags, int xcd, u32 k) {
    __syncthreads();
    if (threadIdx.x == 0)
        __hip_atomic_store(&flags[blockIdx.x * 16], k, __ATOMIC_RELAXED, SCOPE_AGT);
    if (threadIdx.x < 64) {
        const u32* fp = &flags[(xcd + (int)threadIdx.x * 8) * 16];
        for (;;) {
            u32 v = __hip_atomic_load(fp, __ATOMIC_RELAXED, SCOPE_AGT);
            if (__all((int)(v >= k))) break;
            __builtin_amdgcn_s_sleep(2);
        }
    }
    if (threadIdx.x == 0) asm volatile("buffer_inv" ::: "memory");
    __syncthreads();
}

// ---------------- params ----------------
struct AllP {
    const u16 *Xh, *Xl, *Yh, *Yl;
    const float* ebi[4];
    const float* ebh[4];
    const float *b19, *b21, *b23, *b25, *b28, *b29, *b31, *b33, *b35;
    const u16* Wenc[4];
    const u16 *Wm1, *Wm2, *Wmu, *Wlv, *Wcg, *Wdg, *Wd1, *Wd2, *Wdo;
    u16 *encHh, *encHl, *decHh, *decHl;
    u16 *HXYh, *HXYl, *H1h, *H1l, *H2h, *H2l, *muh, *mul2, *Ydh, *Ydl;
    float* CGF;
    float *outY, *muF, *lvF;
    u32* xflags;
};

// ---------------- ring-4 staged GEMM: W + A both via gll16, depth-3 lookahead -------
// Per substep per wave: OPSW = ceil(2*CF/4) W-gll16 (dup when uneven) + 2 A-gll16.
// Slot (u16): [0, CF*1024) W frags; [CF*1024, CF*1024+4096) A (1024/wave).
template <int CF, int NS>
__device__ __forceinline__ void pstage_r4(
    u16* sm, int row0, int fbase,
    const u16* __restrict__ A1h, const u16* __restrict__ A1l, int ld1, int K1,
    const u16* __restrict__ A2h, const u16* __restrict__ A2l, int ld2,
    const u16* __restrict__ Wp, int NF,
    const float* __restrict__ b1, const float* __restrict__ b2, int ACT,
    float* __restrict__ outFrag, int fragbase,
    u16* __restrict__ Oh, u16* __restrict__ Ol, int ldop,
    int wid, int l, int lr, int lk8, int l4) {
    constexpr int OPSW = (2 * CF + 3) / 4;
    constexpr int OPS = OPSW + 2;
    constexpr int SLOTU = CF * 1024 + 4096;

    auto stage = [&](int s) {
        u16* slot = sm + (s & 3) * SLOTU;
#pragma unroll
        for (int j = 0; j < OPSW; ++j) {
            int c = (wid + 4 * j) % (2 * CF);
            gll16(Wp + (size_t)(s * NF + fbase + (c >> 1)) * 1024 + (c & 1) * 512 + l * 8,
                  slot + (c >> 1) * 1024 + (c & 1) * 512);
        }
        int kb = s * 32;
        const u16* ph = (kb < K1) ? A1h : A2h;
        const u16* pl2 = (kb < K1) ? A1l : A2l;
        int ld = (kb < K1) ? ld1 : ld2;
        int koff = (kb < K1) ? kb : (kb - K1);
        size_t so = (size_t)(row0 + lr) * ld + koff + lk8;
        gll16(ph + so, slot + CF * 1024 + wid * 1024);
        gll16(pl2 + so, slot + CF * 1024 + wid * 1024 + 512);
    };

    f32x4 acc[CF] = {};
    stage(0);
    if (NS > 1) stage(1);
    if (NS > 2) stage(2);

#pragma unroll
    for (int s = 0; s < NS; ++s) {
        constexpr int dummy = 0; (void)dummy;
        int rem = NS - 1 - s;
        if (rem > 2) rem = 2;
        if (rem == 2)
            asm volatile("s_waitcnt vmcnt(%0)" ::"i"(2 * OPS) : "memory");
        else if (rem == 1)
            asm volatile("s_waitcnt vmcnt(%0)" ::"i"(OPS) : "memory");
        else
            asm volatile("s_waitcnt vmcnt(0)" ::: "memory");
        __builtin_amdgcn_s_barrier();
        __builtin_amdgcn_sched_barrier(0);
        if (s + 3 < NS) stage(s + 3);
        const u16* slot = sm + (s & 3) * SLOTU;
        s16x8 ah = *(const s16x8*)(slot + CF * 1024 + wid * 1024 + l * 8);
        s16x8 al = *(const s16x8*)(slot + CF * 1024 + wid * 1024 + 512 + l * 8);
#pragma unroll
        for (int cf = 0; cf < CF; ++cf) {
            s16x8 wh = *(const s16x8*)(slot + cf * 1024 + l * 8);
            s16x8 wl = *(const s16x8*)(slot + cf * 1024 + 512 + l * 8);
            mma3(acc[cf], ah, al, wh, wl);
        }
    }
#pragma unroll
    for (int cf = 0; cf < CF; ++cf) {
        int col = (fbase + cf) * 16 + lr;
        float bv = (b1 ? b1[col] : 0.f) + (b2 ? b2[col] : 0.f);
        f32x4 v4;
#pragma unroll
        for (int r = 0; r < 4; ++r) {
            float v = acc[cf][r] + bv;
            if (ACT) v = tanh_fast(v);
            v4[r] = v;
            int row = row0 + l4 + r;
            if (Oh) split_store(v, Oh, Ol, (size_t)row * ldop + col);
        }
        if (outFrag) *(f32x4*)(outFrag + (size_t)(fragbase + cf) * 256 + l * 4) = v4;
    }
}

// ---------------- ring-4 decoder gates + cell (4 gate frags per block) ----------------
template <int NS>
__device__ __forceinline__ void dgates_r4(
    u16* sm, int row0, int ct, int RT,
    const u16* __restrict__ yph, const u16* __restrict__ ypl,
    const u16* __restrict__ Hch, const u16* __restrict__ Hcl,
    const u16* __restrict__ Wp, const float* __restrict__ CGF,
    u16* __restrict__ Hnh, u16* __restrict__ Hnl, float* cds, int t,
    int wid, int l, int lr, int lk8, int l4) {
    constexpr int OPS = 4;       // 2 W + 2 A per wave
    constexpr int SLOTU = 8192;  // 4 frags * 1024 + 4096 A

    auto stage = [&](int s) {
        u16* slot = sm + (s & 3) * SLOTU;
#pragma unroll
        for (int j = 0; j < 2; ++j) {
            int c = wid + 4 * j;  // 0..7
            gll16(Wp + (size_t)(s * 128 + (c >> 1) * 32 + ct) * 1024 + (c & 1) * 512 + l * 8,
                  slot + (c >> 1) * 1024 + (c & 1) * 512);
        }
        int kb = s * 32;
        const u16* ph = (kb < 64) ? yph : Hch;
        const u16* pl2 = (kb < 64) ? ypl : Hcl;
        int ld = (kb < 64) ? 64 : 512;
        int koff = (kb < 64) ? kb : (kb - 64);
        size_t so = (size_t)(row0 + lr) * ld + koff + lk8;
        gll16(ph + so, slot + 4096 + wid * 1024);
        gll16(pl2 + so, slot + 4096 + wid * 1024 + 512);
    };

    f32x4 acc[4];
#pragma unroll
    for (int q = 0; q < 4; ++q)
        acc[q] = *(const f32x4*)(CGF + (size_t)(RT * 128 + q * 32 + ct) * 256 + l * 4);

    stage(0);
    if (NS > 1) stage(1);
    if (NS > 2) stage(2);

#pragma unroll
    for (int s = 0; s < NS; ++s) {
        int rem = NS - 1 - s;
        if (rem > 2) rem = 2;
        if (rem == 2)
            asm volatile("s_waitcnt vmcnt(%0)" ::"i"(2 * OPS) : "memory");
        else if (rem == 1)
            asm volatile("s_waitcnt vmcnt(%0)" ::"i"(OPS) : "memory");
        else
            asm volatile("s_waitcnt vmcnt(0)" ::: "memory");
        __builtin_amdgcn_s_barrier();
        __builtin_amdgcn_sched_barrier(0);
        if (s + 3 < NS) stage(s + 3);
        const u16* slot = sm + (s & 3) * SLOTU;
        s16x8 ah = *(const s16x8*)(slot + 4096 + wid * 1024 + l * 8);
        s16x8 al = *(const s16x8*)(slot + 4096 + wid * 1024 + 512 + l * 8);
#pragma unroll
        for (int q = 0; q < 4; ++q) {
            s16x8 wh = *(const s16x8*)(slot + q * 1024 + l * 8);
            s16x8 wl = *(const s16x8*)(slot + q * 1024 + 512 + l * 8);
            mma3(acc[q], ah, al, wh, wl);
        }
    }
    const int hc = ct * 16 + lr;
#pragma unroll
    for (int r = 0; r < 4; ++r) {
        int row = row0 + l4 + r;
        size_t co = (size_t)row * 512 + hc;
        float gi = sigf(acc[0][r]);
        float gf = sigf(acc[1][r]);
        float gg = tanh_fast(acc[2][r]);
        float go = sigf(acc[3][r]);
        float cold = (t == 0) ? 0.f : cds[r];
        float cn = gf * cold + gi * gg;
        float hn = go * tanh_fast(cn);
        cds[r] = cn;
        split_store(hn, Hnh, Hnl, co);
    }
}

// ---------------- direct-load GEMM (small weights) ----------------
template <int CF>
__device__ __forceinline__ void pdirect_gemm(
    int ns, int row0, int fbase,
    const u16* __restrict__ A1h, const u16* __restrict__ A1l, int ld1,
    const u16* __restrict__ Wp, int NF,
    const float* __restrict__ b1, int ACT,
    float* __restrict__ outF, int ldo,
    u16* __restrict__ Oh, u16* __restrict__ Ol, int ldop,
    int l, int lr, int lk8, int l4) {
    const s16x8* wp = (const s16x8*)Wp;
    const int rowA = row0 + lr;
    f32x4 acc[CF] = {};
    for (int s = 0; s < ns; ++s) {
        int kb = s * 32 + lk8;
        size_t off = (size_t)rowA * ld1 + kb;
        s16x8 ah = *(const s16x8*)(A1h + off), al = *(const s16x8*)(A1l + off);
#pragma unroll
        for (int cf = 0; cf < CF; ++cf) {
            int fi = s * NF + fbase + cf;
            mma3(acc[cf], ah, al, wp[fi * 128 + l], wp[fi * 128 + 64 + l]);
        }
    }
#pragma unroll
    for (int cf = 0; cf < CF; ++cf) {
        int col = (fbase + cf) * 16 + lr;
        float bv = b1 ? b1[col] : 0.f;
#pragma unroll
        for (int r = 0; r < 4; ++r) {
            float v = acc[cf][r] + bv;
            if (ACT) v = tanh_fast(v);
            int row = row0 + l4 + r;
            if (outF) outF[(size_t)row * ldo + col] = v;
            if (Oh) split_store(v, Oh, Ol, (size_t)row * ldop + col);
        }
    }
}

// ================ kernel 1: encoder (XCD-local, direct loads) ================
__global__ __launch_bounds__(256, 2) void enc_persist(AllP P) {
    const int tid = threadIdx.x, b = blockIdx.x;
    const int wid = tid >> 6, l = tid & 63;
    const int lr = l & 15, lk8 = (l >> 4) * 8, l4 = (l >> 4) * 4;
    const int xcd = b & 7, bm = b >> 3;
    u32 xk = 0;

    const int scan = xcd >> 1;
    const int rowbase = (xcd & 1) * 512;
    const int T = (scan < 2) ? 64 : 100;
    const int rev = scan & 1;
    const u16* Xb = (scan < 2) ? P.Xh : P.Yh;
    const u16* Xlb = (scan < 2) ? P.Xl : P.Yl;
    const s16x8* wp = (const s16x8*)P.Wenc[scan];
    const float* bi = P.ebi[scan];
    const float* bh = P.ebh[scan];
    u16* Hhb = P.encHh + (size_t)scan * 524288;
    u16* Hlb = P.encHl + (size_t)scan * 524288;
    const int rt = bm >> 3, ct = bm & 7;
    const int row0 = rowbase + rt * 64 + wid * 16;
    const int rowA = row0 + lr;
    const int hc0 = ct * 32;
    float cst[2][4] = {};
    float hsr[2][4] = {};

    for (int t = 0; t < T; ++t) {
        const int tt = rev ? (T - 1 - t) : t;
        const u16* xh = Xb + (size_t)tt * 65536;
        const u16* xl = Xlb + (size_t)tt * 65536;
        const u16* Hch = Hhb + (size_t)(t & 1) * 262144;
        const u16* Hcl = Hlb + (size_t)(t & 1) * 262144;
        u16* Hnh = Hhb + (size_t)((t + 1) & 1) * 262144;
        u16* Hnl = Hlb + (size_t)((t + 1) & 1) * 262144;
        f32x4 acc[4][2];
#pragma unroll
        for (int q = 0; q < 4; ++q)
#pragma unroll
            for (int cf = 0; cf < 2; ++cf) {
                int col = q * 256 + hc0 + cf * 16 + lr;
                float bv = bi[col] + bh[col];
                acc[q][cf] = (f32x4){bv, bv, bv, bv};
            }
        const int NS = (t == 0) ? 2 : 10;
        for (int s = 0; s < NS; ++s) {
            int kb = s * 32 + lk8;
            const u16* ph = (kb < 64) ? xh : Hch;
            const u16* pl2 = (kb < 64) ? xl : Hcl;
            size_t off = (kb < 64) ? ((size_t)rowA * 64 + kb)
                                   : ((size_t)rowA * 256 + (kb - 64));
            s16x8 ah = *(const s16x8*)(ph + off), al = *(const s16x8*)(pl2 + off);
#pragma unroll
            for (int q = 0; q < 4; ++q)
#pragma unroll
                for (int cf = 0; cf < 2; ++cf) {
                    int fi = s * 64 + q * 16 + ct * 2 + cf;
                    mma3(acc[q][cf], ah, al, wp[fi * 128 + l], wp[fi * 128 + 64 + l]);
                }
        }
#pragma unroll
        for (int cf = 0; cf < 2; ++cf) {
            int hc = hc0 + cf * 16 + lr;
#pragma unroll
            for (int r = 0; r < 4; ++r) {
                int row = row0 + l4 + r;
                size_t co = (size_t)row * 256 + hc;
                float gi = sigf(acc[0][cf][r]);
                float gf = sigf(acc[1][cf][r]);
                float gg = tanh_fast(acc[2][cf][r]);
                float go = sigf(acc[3][cf][r]);
                float cn = gf * cst[cf][r] + gi * gg;
                float hn = go * tanh_fast(cn);
                cst[cf][r] = cn;
                hsr[cf][r] += hn;
                split_store(hn, Hnh, Hnl, co);
            }
        }
        barx(P.xflags, xcd, ++xk);
    }
    float sc = (scan < 2) ? (1.f / 64.f) : (1.f / 100.f);
#pragma unroll
    for (int cf = 0; cf < 2; ++cf) {
        int col = scan * 256 + hc0 + cf * 16 + lr;
#pragma unroll
        for (int r = 0; r < 4; ++r) {
            int row = row0 + l4 + r;
            split_store(hsr[cf][r] * sc, P.HXYh, P.HXYl, (size_t)row * 1024 + col);
        }
    }
}

// ================ kernel 2: middle + decoder (ring-4 pipelines) ================
__global__ __launch_bounds__(256, 2) void mid_dec(AllP P) {
    __shared__ u16 sm[32768];  // 64 KB ring-4 staging
    const int tid = threadIdx.x, b = blockIdx.x;
    const int wid = tid >> 6, l = tid & 63;
    const int lr = l & 15, lk8 = (l >> 4) * 8, l4 = (l >> 4) * 4;
    const int xcd = b & 7, bm = b >> 3;
    u32 xk = 200;  // encoder left flags at 64/100

    // ---- middle ----
    {
        const int rt = bm & 1, ct = bm >> 1;
        pstage_r4<2, 32>(sm, xcd * 128 + rt * 64 + wid * 16, ct * 2,
                         P.HXYh, P.HXYl, 1024, 4096, P.HXYh, P.HXYl, 1024,
                         P.Wm1, 64, P.b19, nullptr, 1,
                         nullptr, 0, P.H1h, P.H1l, 1024, wid, l, lr, lk8, l4);
    }
    barx(P.xflags, xcd, ++xk);
    {
        const int rt = bm & 1, ct = bm >> 1;
        pstage_r4<1, 32>(sm, xcd * 128 + rt * 64 + wid * 16, ct,
                         P.H1h, P.H1l, 1024, 4096, P.H1h, P.H1l, 1024,
                         P.Wm2, 32, P.b21, nullptr, 1,
                         nullptr, 0, P.H2h, P.H2l, 512, wid, l, lr, lk8, l4);
    }
    barx(P.xflags, xcd, ++xk);
    {
        if (bm < 16) {
            const int rt = bm & 1, cfi = bm >> 1;
            pdirect_gemm<1>(16, xcd * 128 + rt * 64 + wid * 16, cfi,
                            P.H2h, P.H2l, 512, P.Wmu, 8, P.b23, 0,
                            P.muF, 128, P.muh, P.mul2, 128, l, lr, lk8, l4);
        } else if (bm < 32) {
            const int bm2 = bm - 16;
            const int rt = bm2 & 1, cfi = bm2 >> 1;
            pdirect_gemm<1>(16, xcd * 128 + rt * 64 + wid * 16, cfi,
                            P.H2h, P.H2l, 512, P.Wlv, 8, P.b25, 0,
                            P.lvF, 128, nullptr, nullptr, 0, l, lr, lk8, l4);
        }
    }
    barx(P.xflags, xcd, ++xk);
    {
        const int rt = bm & 1, ct = bm >> 1;
        const int fragbase = (xcd * 8 + rt * 4 + wid) * 128 + ct * 4;
        pstage_r4<4, 20>(sm, xcd * 128 + rt * 64 + wid * 16, ct * 4,
                         P.HXYh, P.HXYl, 1024, 512, P.muh, P.mul2, 128,
                         P.Wcg, 128, P.b28, P.b29, 0,
                         P.CGF, fragbase, nullptr, nullptr, 0, wid, l, lr, lk8, l4);
    }
    barx(P.xflags, xcd, ++xk);

    // ---- decoder ----
    float cds[4] = {};
    for (int t = 0; t < 100; ++t) {
        {
            const int rt = bm >> 5, ct = bm & 31;
            const int row0 = xcd * 128 + rt * 64 + wid * 16;
            const int RT = xcd * 8 + rt * 4 + wid;
            const u16* yph = (t == 0) ? (P.Xh + (size_t)63 * 65536) : P.Ydh;
            const u16* ypl = (t == 0) ? (P.Xl + (size_t)63 * 65536) : P.Ydl;
            const u16* Hch = P.decHh + (size_t)(t & 1) * 524288;
            const u16* Hcl = P.decHl + (size_t)(t & 1) * 524288;
            u16* Hnh = P.decHh + (size_t)((t + 1) & 1) * 524288;
            u16* Hnl = P.decHl + (size_t)((t + 1) & 1) * 524288;
            if (t == 0)
                dgates_r4<2>(sm, row0, ct, RT, yph, ypl, Hch, Hcl, P.Wdg, P.CGF,
                             Hnh, Hnl, cds, t, wid, l, lr, lk8, l4);
            else
                dgates_r4<18>(sm, row0, ct, RT, yph, ypl, Hch, Hcl, P.Wdg, P.CGF,
                              Hnh, Hnl, cds, t, wid, l, lr, lk8, l4);
        }
        barx(P.xflags, xcd, ++xk);
        {
            const u16* Hnh = P.decHh + (size_t)((t + 1) & 1) * 524288;
            const u16* Hnl = P.decHl + (size_t)((t + 1) & 1) * 524288;
            const int rt = bm & 1, ct = bm >> 1;
            pstage_r4<2, 16>(sm, xcd * 128 + rt * 64 + wid * 16, ct * 2,
                             Hnh, Hnl, 512, 4096, Hnh, Hnl, 512,
                             P.Wd1, 64, P.b31, nullptr, 1,
                             nullptr, 0, P.H1h, P.H1l, 1024, wid, l, lr, lk8, l4);
        }
        barx(P.xflags, xcd, ++xk);
        {
            const int rt = bm & 1, ct = bm >> 1;
            pstage_r4<1, 32>(sm, xcd * 128 + rt * 64 + wid * 16, ct,
                             P.H1h, P.H1l, 1024, 4096, P.H1h, P.H1l, 1024,
                             P.Wd2, 32, P.b33, nullptr, 1,
                             nullptr, 0, P.H2h, P.H2l, 512, wid, l, lr, lk8, l4);
        }
        barx(P.xflags, xcd, ++xk);
        if (bm < 2)
            pdirect_gemm<4>(16, xcd * 128 + bm * 64 + wid * 16, 0,
                            P.H2h, P.H2l, 512, P.Wdo, 4, P.b35, 0,
                            P.outY + (size_t)t * 65536, 64,
                            P.Ydh, P.Ydl, 64, l, lr, lk8, l4);
        barx(P.xflags, xcd, ++xk);
    }
}

// ---------------- host ----------------
extern "C" void kernel_launch(void* const* d_in, const int* in_sizes, int n_in,
                              void* d_out, int out_size, void* d_ws, size_t ws_size,
                              hipStream_t stream) {
    (void)in_sizes; (void)n_in; (void)out_size; (void)ws_size;
    auto F = [&](int i) { return (const float*)d_in[i]; };
    const float* x = F(0);
    const float* y = F(1);
    float* out = (float*)d_out;
    char* base = (char*)d_ws;
    const size_t MB = 1ull << 20;
    const size_t KB = 1024;

    AllP P;
    P.xflags = (u32*)base;                       // 32 KB
    char* p = base + 64 * KB;
    P.CGF = (float*)p; p += 8 * MB;
    P.encHh = (u16*)p; p += 4 * MB;
    P.encHl = (u16*)p; p += 4 * MB;
    P.decHh = (u16*)p; p += 2 * MB;
    P.decHl = (u16*)p; p += 2 * MB;
    P.HXYh = (u16*)p; p += 2 * MB;
    P.HXYl = (u16*)p; p += 2 * MB;
    P.H1h = (u16*)p; p += 2 * MB;
    P.H1l = (u16*)p; p += 2 * MB;
    P.H2h = (u16*)p; p += 1 * MB;
    P.H2l = (u16*)p; p += 1 * MB;
    P.muh = (u16*)p; p += 256 * KB;
    P.mul2 = (u16*)p; p += 256 * KB;
    P.Ydh = (u16*)p; p += 128 * KB;
    P.Ydl = (u16*)p; p += 128 * KB;
    u16* Xh = (u16*)p; p += 8 * MB;
    u16* Xl = (u16*)p; p += 8 * MB;
    u16* Yh = (u16*)p; p += (size_t)100 * 1024 * 64 * 2;
    u16* Yl = (u16*)p; p += (size_t)100 * 1024 * 64 * 2;
    u16* W0 = (u16*)p;

    size_t wo = 0;
    auto walloc = [&](size_t elems) { u16* q = W0 + wo; wo += elems * 2; return q; };
    u16* WPX0 = walloc((size_t)1024 * 320);
    u16* WPX1 = walloc((size_t)1024 * 320);
    u16* WPE0 = walloc((size_t)1024 * 320);
    u16* WPE1 = walloc((size_t)1024 * 320);
    u16* WPM1 = walloc((size_t)1024 * 1024);
    u16* WPM2 = walloc((size_t)512 * 1024);
    u16* WPMU = walloc((size_t)128 * 512);
    u16* WPLV = walloc((size_t)128 * 512);
    u16* WPCG = walloc((size_t)2048 * 640);
    u16* WPDG = walloc((size_t)2048 * 576);
    u16* WPD1 = walloc((size_t)1024 * 512);
    u16* WPD2 = walloc((size_t)512 * 1024);
    u16* WPDO = walloc((size_t)64 * 512);

    auto prep = [&](const float* s1, int ld1, int k1, const float* s2, int ld2,
                    u16* o, int N, int KT) {
        prep_w<<<(N * KT / 8) / 256, 256, 0, stream>>>(s1, ld1, k1, s2, ld2, o, N / 16);
    };
    prep(F(2), 64, 64, F(3), 256, WPX0, 1024, 320);
    prep(F(6), 64, 64, F(7), 256, WPX1, 1024, 320);
    prep(F(10), 64, 64, F(11), 256, WPE0, 1024, 320);
    prep(F(14), 64, 64, F(15), 256, WPE1, 1024, 320);
    prep(F(18), 1024, 1024, F(18), 1024, WPM1, 1024, 1024);
    prep(F(20), 1024, 1024, F(20), 1024, WPM2, 512, 1024);
    prep(F(22), 512, 512, F(22), 512, WPMU, 128, 512);
    prep(F(24), 512, 512, F(24), 512, WPLV, 128, 512);
    prep(F(26), 704, 640, F(26), 704, WPCG, 2048, 640);
    prep(F(26) + 640, 704, 64, F(27), 512, WPDG, 2048, 576);
    prep(F(30), 512, 512, F(30), 512, WPD1, 1024, 512);
    prep(F(32), 1024, 1024, F(32), 1024, WPD2, 512, 1024);
    prep(F(34), 512, 512, F(34), 512, WPDO, 64, 512);

    prep_act<<<4096, 256, 0, stream>>>(x, Xh, Xl, 64 * 1024 * 64 / 4);
    prep_act<<<6400, 256, 0, stream>>>(y, Yh, Yl, 100 * 1024 * 64 / 4);

    hipMemsetAsync(base, 0, 64 * KB, stream);  // barrier flags

    P.Xh = Xh; P.Xl = Xl; P.Yh = Yh; P.Yl = Yl;
    const int wi[4] = {2, 6, 10, 14};
    u16* wps[4] = {WPX0, WPX1, WPE0, WPE1};
    for (int s = 0; s < 4; ++s) {
        P.Wenc[s] = wps[s];
        P.ebi[s] = F(wi[s] + 2);
        P.ebh[s] = F(wi[s] + 3);
    }
    P.Wm1 = WPM1; P.Wm2 = WPM2; P.Wmu = WPMU; P.Wlv = WPLV;
    P.Wcg = WPCG; P.Wdg = WPDG; P.Wd1 = WPD1; P.Wd2 = WPD2; P.Wdo = WPDO;
    P.b19 = F(19); P.b21 = F(21); P.b23 = F(23); P.b25 = F(25);
    P.b28 = F(28); P.b29 = F(29); P.b31 = F(31); P.b33 = F(33); P.b35 = F(35);
    P.outY = out;
    P.muF = out + (size_t)100 * 1024 * 64;
    P.lvF = P.muF + (size_t)1024 * 128;

    enc_persist<<<512, 256, 0, stream>>>(P);
    mid_dec<<<512, 256, 0, stream>>>(P);
}

// Round 15
// 8535.709 us; speedup vs baseline: 1.7307x; 1.7307x over previous
//
#include <hip/hip_runtime.h>

typedef unsigned short u16;
typedef unsigned int u32;
typedef __attribute__((ext_vector_type(8))) short s16x8;
typedef __attribute__((ext_vector_type(4))) float f32x4;

#define MFMA_BF16 __builtin_amdgcn_mfma_f32_16x16x32_bf16
#define SCOPE_AGT __HIP_MEMORY_SCOPE_AGENT

__device__ __forceinline__ float sigf(float x) { return 1.f / (1.f + __expf(-x)); }
__device__ __forceinline__ float tanh_fast(float x) {
    float e = __expf(2.f * x);
    return 1.f - 2.f / (e + 1.f);
}
__device__ __forceinline__ u16 bf16_rn(float x) {
    u32 u = __float_as_uint(x);
    u += 0x7FFFu + ((u >> 16) & 1u);
    return (u16)(u >> 16);
}
__device__ __forceinline__ void split_store(float v, u16* __restrict__ ph,
                                            u16* __restrict__ pl, size_t off) {
    u16 h = bf16_rn(v);
    float hf = __uint_as_float(((u32)h) << 16);
    ph[off] = h;
    pl[off] = bf16_rn(v - hf);
}
__device__ __forceinline__ void mma3(f32x4& acc, s16x8 ah, s16x8 al, s16x8 wh, s16x8 wl) {
    acc = MFMA_BF16(ah, wh, acc, 0, 0, 0);
    acc = MFMA_BF16(al, wh, acc, 0, 0, 0);
    acc = MFMA_BF16(ah, wl, acc, 0, 0, 0);
}
__device__ __forceinline__ void gll16(const u16* g, u16* l) {
    __builtin_amdgcn_global_load_lds(
        (const __attribute__((address_space(1))) u32*)g,
        (__attribute__((address_space(3))) u32*)l, 16, 0, 0);
}

// ---------------- weight prep: fragment blocks, plane-separated ----------------
__global__ __launch_bounds__(256) void prep_w(const float* __restrict__ S1, int ld1, int K1,
                                              const float* __restrict__ S2, int ld2,
                                              u16* __restrict__ out, int NF) {
    int idx = blockIdx.x * 256 + threadIdx.x;
    int l = idx & 63;
    int u = idx >> 6;
    int f = u % NF;
    int s = u / NF;
    int n = f * 16 + (l & 15);
    int kb = s * 32 + ((l >> 4) << 3);
    u16* o = out + (size_t)u * 1024 + l * 8;
#pragma unroll
    for (int j = 0; j < 8; ++j) {
        int k = kb + j;
        float v = (k < K1) ? S1[(size_t)n * ld1 + k] : S2[(size_t)n * ld2 + (k - K1)];
        u16 h = bf16_rn(v);
        float hf = __uint_as_float(((u32)h) << 16);
        o[j] = h;
        o[512 + j] = bf16_rn(v - hf);
    }
}

__global__ __launch_bounds__(256) void prep_act(const float* __restrict__ in,
                                                u16* __restrict__ hi, u16* __restrict__ lo,
                                                int n4) {
    int i = blockIdx.x * 256 + threadIdx.x;
    if (i >= n4) return;
    float4 v = ((const float4*)in)[i];
    float vv[4] = {v.x, v.y, v.z, v.w};
    u16 h[4], lw[4];
#pragma unroll
    for (int j = 0; j < 4; ++j) {
        h[j] = bf16_rn(vv[j]);
        float hf = __uint_as_float(((u32)h[j]) << 16);
        lw[j] = bf16_rn(vv[j] - hf);
    }
    ((ushort4*)hi)[i] = make_ushort4(h[0], h[1], h[2], h[3]);
    ((ushort4*)lo)[i] = make_ushort4(lw[0], lw[1], lw[2], lw[3]);
}

// ---------------- barriers ----------------
__device__ __forceinline__ void barx(u32* __restrict__ flags, int xcd, u32 k) {
    __syncthreads();
    if (threadIdx.x == 0)
        __hip_atomic_store(&flags[blockIdx.x * 16], k, __ATOMIC_RELAXED, SCOPE_AGT);
    if (threadIdx.x < 64) {
        const u32* fp = &flags[(xcd + (int)threadIdx.x * 8) * 16];
        for (;;) {
            u32 v = __hip_atomic_load(fp, __ATOMIC_RELAXED, SCOPE_AGT);
            if (__all((int)(v >= k))) break;
            __builtin_amdgcn_s_sleep(2);
        }
    }
    if (threadIdx.x == 0) asm volatile("buffer_inv" ::: "memory");
    __syncthreads();
}

__device__ __forceinline__ void barg(u32* __restrict__ flags, u32 k) {
    __syncthreads();
    if (threadIdx.x == 0) {
        __builtin_amdgcn_fence(__ATOMIC_RELEASE, "agent");
        __hip_atomic_store(&flags[blockIdx.x * 16], k, __ATOMIC_RELAXED, SCOPE_AGT);
    }
    if (threadIdx.x < 64) {
        for (;;) {
            u32 mn = 0xFFFFFFFFu;
#pragma unroll
            for (int j = 0; j < 8; ++j) {
                u32 v = __hip_atomic_load(&flags[((int)threadIdx.x * 8 + j) * 16],
                                          __ATOMIC_RELAXED, SCOPE_AGT);
                mn = v < mn ? v : mn;
            }
            if (__all((int)(mn >= k))) break;
            __builtin_amdgcn_s_sleep(8);
        }
    }
    if (threadIdx.x == 0) __builtin_amdgcn_fence(__ATOMIC_ACQUIRE, "agent");
    __syncthreads();
}

// ---------------- params ----------------
struct AllP {
    const u16 *Xh, *Xl, *Yh, *Yl;
    const float* ebi[4];
    const float* ebh[4];
    const float *b19, *b21, *b23, *b25, *b28, *b29, *b31, *b33, *b35;
    const u16* Wenc[4];
    const u16 *Wm1, *Wm2, *Wmu, *Wlv, *Wcg, *Wdg, *Wd1, *Wd2, *Wdo;
    u16 *encHh, *encHl, *decHh, *decHl;
    u16 *HXYh, *HXYl, *H1h, *H1l, *H2h, *H2l, *muh, *mul2, *Ydh, *Ydl;
    float* CGF;
    float *outY, *muF, *lvF;
    u32 *gflags, *xflags;
};

// ---------------- staged GEMM, BK=64 substeps (R11 dbuf semantics) ----------------
// Per substep: stage 2 k-slices (2*CF frag-blocks, 4*CF 1KB-chunks over 4 waves),
// compute 2 slices (2 direct A-loads + 2*CF mma3). __syncthreads drains at end.
template <int CF>
__device__ __forceinline__ void pstage_gemm(
    u16* sm, int nd, int row0, int fbase,
    const u16* __restrict__ A1h, const u16* __restrict__ A1l, int ld1, int K1,
    const u16* __restrict__ A2h, const u16* __restrict__ A2l, int ld2,
    const u16* __restrict__ Wp, int NF,
    const float* __restrict__ b1, const float* __restrict__ b2, int ACT,
    float* __restrict__ outFrag, int fragbase,
    u16* __restrict__ Oh, u16* __restrict__ Ol, int ldop,
    int wid, int l, int lr, int lk8, int l4) {
    const int rowA = row0 + lr;
    constexpr int SLOT = 2 * CF * 1024;  // u16 per buffer

    auto stage = [&](int d, int buf) {
        u16* dst = sm + buf * SLOT;
#pragma unroll
        for (int c = 0; c < CF; ++c) {
            int ch = wid + 4 * c;  // 0..4*CF-1, exact cover
            int slice = ch / (2 * CF);
            int rem = ch % (2 * CF);
            int f = rem >> 1, half = rem & 1;
            gll16(Wp + (size_t)((2 * d + slice) * NF + fbase + f) * 1024 + half * 512 + l * 8,
                  dst + slice * CF * 1024 + f * 1024 + half * 512);
        }
    };

    f32x4 acc[CF] = {};
    stage(0, 0);
    __syncthreads();
    for (int d = 0; d < nd; ++d) {
        if (d + 1 < nd) stage(d + 1, (d + 1) & 1);
        const u16* cur = sm + (d & 1) * SLOT;
#pragma unroll
        for (int sl = 0; sl < 2; ++sl) {
            int kb = d * 64 + sl * 32 + lk8;
            const u16* ph = (kb < K1) ? A1h : A2h;
            const u16* pl2 = (kb < K1) ? A1l : A2l;
            size_t off = (kb < K1) ? ((size_t)rowA * ld1 + kb)
                                   : ((size_t)rowA * ld2 + (kb - K1));
            s16x8 ah = *(const s16x8*)(ph + off), al = *(const s16x8*)(pl2 + off);
#pragma unroll
            for (int cf = 0; cf < CF; ++cf) {
                s16x8 wh = *(const s16x8*)(cur + sl * CF * 1024 + cf * 1024 + l * 8);
                s16x8 wl = *(const s16x8*)(cur + sl * CF * 1024 + cf * 1024 + 512 + l * 8);
                mma3(acc[cf], ah, al, wh, wl);
            }
        }
        __syncthreads();
    }
#pragma unroll
    for (int cf = 0; cf < CF; ++cf) {
        int col = (fbase + cf) * 16 + lr;
        float bv = (b1 ? b1[col] : 0.f) + (b2 ? b2[col] : 0.f);
        f32x4 v4;
#pragma unroll
        for (int r = 0; r < 4; ++r) {
            float v = acc[cf][r] + bv;
            if (ACT) v = tanh_fast(v);
            v4[r] = v;
            int row = row0 + l4 + r;
            if (Oh) split_store(v, Oh, Ol, (size_t)row * ldop + col);
        }
        if (outFrag) *(f32x4*)(outFrag + (size_t)(fragbase + cf) * 256 + l * 4) = v4;
    }
}

// ---------------- direct-load GEMM (small weights) ----------------
template <int CF>
__device__ __forceinline__ void pdirect_gemm(
    int ns, int row0, int fbase,
    const u16* __restrict__ A1h, const u16* __restrict__ A1l, int ld1,
    const u16* __restrict__ Wp, int NF,
    const float* __restrict__ b1, int ACT,
    float* __restrict__ outF, int ldo,
    u16* __restrict__ Oh, u16* __restrict__ Ol, int ldop,
    int l, int lr, int lk8, int l4) {
    const s16x8* wp = (const s16x8*)Wp;
    const int rowA = row0 + lr;
    f32x4 acc[CF] = {};
    for (int s = 0; s < ns; ++s) {
        int kb = s * 32 + lk8;
        size_t off = (size_t)rowA * ld1 + kb;
        s16x8 ah = *(const s16x8*)(A1h + off), al = *(const s16x8*)(A1l + off);
#pragma unroll
        for (int cf = 0; cf < CF; ++cf) {
            int fi = s * NF + fbase + cf;
            mma3(acc[cf], ah, al, wp[fi * 128 + l], wp[fi * 128 + 64 + l]);
        }
    }
#pragma unroll
    for (int cf = 0; cf < CF; ++cf) {
        int col = (fbase + cf) * 16 + lr;
        float bv = b1 ? b1[col] : 0.f;
#pragma unroll
        for (int r = 0; r < 4; ++r) {
            float v = acc[cf][r] + bv;
            if (ACT) v = tanh_fast(v);
            int row = row0 + l4 + r;
            if (outF) outF[(size_t)row * ldo + col] = v;
            if (Oh) split_store(v, Oh, Ol, (size_t)row * ldop + col);
        }
    }
}

// ---------------- the persistent kernel: 512 blocks, 2 per CU ----------------
__global__ __launch_bounds__(256, 2) void vae_persist(AllP P) {
    __shared__ u16 sm[16384];  // 32 KB double-buffered staging (BK=64)
    const int tid = threadIdx.x, b = blockIdx.x;
    const int wid = tid >> 6, l = tid & 63;
    const int lr = l & 15, lk8 = (l >> 4) * 8, l4 = (l >> 4) * 4;
    const int xcd = b & 7, bm = b >> 3;  // 64 blocks per XCD group
    u32 xk = 0;

    // ================= encoder: XCD-local (unchanged from R11) =================
    {
        const int scan = xcd >> 1;
        const int rowbase = (xcd & 1) * 512;
        const int T = (scan < 2) ? 64 : 100;
        const int rev = scan & 1;
        const u16* Xb = (scan < 2) ? P.Xh : P.Yh;
        const u16* Xlb = (scan < 2) ? P.Xl : P.Yl;
        const s16x8* wp = (const s16x8*)P.Wenc[scan];
        const float* bi = P.ebi[scan];
        const float* bh = P.ebh[scan];
        u16* Hhb = P.encHh + (size_t)scan * 524288;
        u16* Hlb = P.encHl + (size_t)scan * 524288;
        const int rt = bm >> 3, ct = bm & 7;
        const int row0 = rowbase + rt * 64 + wid * 16;
        const int rowA = row0 + lr;
        const int hc0 = ct * 32;
        float cst[2][4] = {};
        float hsr[2][4] = {};

        for (int t = 0; t < T; ++t) {
            const int tt = rev ? (T - 1 - t) : t;
            const u16* xh = Xb + (size_t)tt * 65536;
            const u16* xl = Xlb + (size_t)tt * 65536;
            const u16* Hch = Hhb + (size_t)(t & 1) * 262144;
            const u16* Hcl = Hlb + (size_t)(t & 1) * 262144;
            u16* Hnh = Hhb + (size_t)((t + 1) & 1) * 262144;
            u16* Hnl = Hlb + (size_t)((t + 1) & 1) * 262144;
            f32x4 acc[4][2];
#pragma unroll
            for (int q = 0; q < 4; ++q)
#pragma unroll
                for (int cf = 0; cf < 2; ++cf) {
                    int col = q * 256 + hc0 + cf * 16 + lr;
                    float bv = bi[col] + bh[col];
                    acc[q][cf] = (f32x4){bv, bv, bv, bv};
                }
            const int NS = (t == 0) ? 2 : 10;
            for (int s = 0; s < NS; ++s) {
                int kb = s * 32 + lk8;
                const u16* ph = (kb < 64) ? xh : Hch;
                const u16* pl2 = (kb < 64) ? xl : Hcl;
                size_t off = (kb < 64) ? ((size_t)rowA * 64 + kb)
                                       : ((size_t)rowA * 256 + (kb - 64));
                s16x8 ah = *(const s16x8*)(ph + off), al = *(const s16x8*)(pl2 + off);
#pragma unroll
                for (int q = 0; q < 4; ++q)
#pragma unroll
                    for (int cf = 0; cf < 2; ++cf) {
                        int fi = s * 64 + q * 16 + ct * 2 + cf;
                        mma3(acc[q][cf], ah, al, wp[fi * 128 + l], wp[fi * 128 + 64 + l]);
                    }
            }
#pragma unroll
            for (int cf = 0; cf < 2; ++cf) {
                int hc = hc0 + cf * 16 + lr;
#pragma unroll
                for (int r = 0; r < 4; ++r) {
                    int row = row0 + l4 + r;
                    size_t co = (size_t)row * 256 + hc;
                    float gi = sigf(acc[0][cf][r]);
                    float gf = sigf(acc[1][cf][r]);
                    float gg = tanh_fast(acc[2][cf][r]);
                    float go = sigf(acc[3][cf][r]);
                    float cn = gf * cst[cf][r] + gi * gg;
                    float hn = go * tanh_fast(cn);
                    cst[cf][r] = cn;
                    hsr[cf][r] += hn;
                    split_store(hn, Hnh, Hnl, co);
                }
            }
            barx(P.xflags, xcd, ++xk);
        }
        float sc = (scan < 2) ? (1.f / 64.f) : (1.f / 100.f);
#pragma unroll
        for (int cf = 0; cf < 2; ++cf) {
            int col = scan * 256 + hc0 + cf * 16 + lr;
#pragma unroll
            for (int r = 0; r < 4; ++r) {
                int row = row0 + l4 + r;
                split_store(hsr[cf][r] * sc, P.HXYh, P.HXYl, (size_t)row * 1024 + col);
            }
        }
    }
    barg(P.gflags, 1);  // the ONLY cross-XCD handoff

    // ================= middle (rows xcd*128..+127, XCD-local) =================
    {
        const int rt = bm & 1, ct = bm >> 1;
        pstage_gemm<2>(sm, 16, xcd * 128 + rt * 64 + wid * 16, ct * 2,
                       P.HXYh, P.HXYl, 1024, 4096, P.HXYh, P.HXYl, 1024,
                       P.Wm1, 64, P.b19, nullptr, 1,
                       nullptr, 0, P.H1h, P.H1l, 1024, wid, l, lr, lk8, l4);
    }
    barx(P.xflags, xcd, ++xk);
    {
        const int rt = bm & 1, ct = bm >> 1;
        pstage_gemm<1>(sm, 16, xcd * 128 + rt * 64 + wid * 16, ct,
                       P.H1h, P.H1l, 1024, 4096, P.H1h, P.H1l, 1024,
                       P.Wm2, 32, P.b21, nullptr, 1,
                       nullptr, 0, P.H2h, P.H2l, 512, wid, l, lr, lk8, l4);
    }
    barx(P.xflags, xcd, ++xk);
    {
        if (bm < 16) {
            const int rt = bm & 1, cfi = bm >> 1;
            pdirect_gemm<1>(16, xcd * 128 + rt * 64 + wid * 16, cfi,
                            P.H2h, P.H2l, 512, P.Wmu, 8, P.b23, 0,
                            P.muF, 128, P.muh, P.mul2, 128, l, lr, lk8, l4);
        } else if (bm < 32) {
            const int bm2 = bm - 16;
            const int rt = bm2 & 1, cfi = bm2 >> 1;
            pdirect_gemm<1>(16, xcd * 128 + rt * 64 + wid * 16, cfi,
                            P.H2h, P.H2l, 512, P.Wlv, 8, P.b25, 0,
                            P.lvF, 128, nullptr, nullptr, 0, l, lr, lk8, l4);
        }
    }
    barx(P.xflags, xcd, ++xk);
    {
        const int rt = bm & 1, ct = bm >> 1;
        const int fragbase = (xcd * 8 + rt * 4 + wid) * 128 + ct * 4;
        pstage_gemm<4>(sm, 10, xcd * 128 + rt * 64 + wid * 16, ct * 4,
                       P.HXYh, P.HXYl, 1024, 512, P.muh, P.mul2, 128,
                       P.Wcg, 128, P.b28, P.b29, 0,
                       P.CGF, fragbase, nullptr, nullptr, 0, wid, l, lr, lk8, l4);
    }
    barx(P.xflags, xcd, ++xk);

    // ================= decoder (rows xcd*128..+127, XCD-local) =================
    float cds[4] = {};
    for (int t = 0; t < 100; ++t) {
        // ---- gates + cell: rt = bm>>5 (0..1), ct = bm&31 (one frag per gate) ----
        {
            const int rt = bm >> 5, ct = bm & 31;
            const int row0 = xcd * 128 + rt * 64 + wid * 16;
            const int rowA = row0 + lr;
            const int RT = xcd * 8 + rt * 4 + wid;
            const u16* yph = (t == 0) ? (P.Xh + (size_t)63 * 65536) : P.Ydh;
            const u16* ypl = (t == 0) ? (P.Xl + (size_t)63 * 65536) : P.Ydl;
            const u16* Hch = P.decHh + (size_t)(t & 1) * 524288;
            const u16* Hcl = P.decHl + (size_t)(t & 1) * 524288;
            u16* Hnh = P.decHh + (size_t)((t + 1) & 1) * 524288;
            u16* Hnl = P.decHl + (size_t)((t + 1) & 1) * 524288;
            auto stg = [&](int d, int buf) {
#pragma unroll
                for (int c = 0; c < 4; ++c) {
                    int ch = wid + 4 * c;  // 0..15
                    int slice = ch >> 3;
                    int rem = ch & 7;
                    int q = rem >> 1, half = rem & 1;
                    gll16(P.Wdg + (size_t)((2 * d + slice) * 128 + q * 32 + ct) * 1024 +
                              half * 512 + l * 8,
                          sm + buf * 8192 + slice * 4096 + q * 1024 + half * 512);
                }
            };
            f32x4 acc[4];
#pragma unroll
            for (int q = 0; q < 4; ++q)
                acc[q] = *(const f32x4*)(P.CGF +
                         (size_t)(RT * 128 + q * 32 + ct) * 256 + l * 4);
            const int nd = (t == 0) ? 1 : 9;
            stg(0, 0);
            __syncthreads();
            for (int d = 0; d < nd; ++d) {
                if (d + 1 < nd) stg(d + 1, (d + 1) & 1);
                const u16* cur = sm + (d & 1) * 8192;
#pragma unroll
                for (int sl = 0; sl < 2; ++sl) {
                    int kb = d * 64 + sl * 32 + lk8;
                    const u16* ph = (kb < 64) ? yph : Hch;
                    const u16* pl2 = (kb < 64) ? ypl : Hcl;
                    size_t off = (kb < 64) ? ((size_t)rowA * 64 + kb)
                                           : ((size_t)rowA * 512 + (kb - 64));
                    s16x8 ah = *(const s16x8*)(ph + off), al = *(const s16x8*)(pl2 + off);
#pragma unroll
                    for (int q = 0; q < 4; ++q) {
                        s16x8 wh = *(const s16x8*)(cur + sl * 4096 + q * 1024 + l * 8);
                        s16x8 wl = *(const s16x8*)(cur + sl * 4096 + q * 1024 + 512 + l * 8);
                        mma3(acc[q], ah, al, wh, wl);
                    }
                }
                __syncthreads();
            }
            const int hc = ct * 16 + lr;
#pragma unroll
            for (int r = 0; r < 4; ++r) {
                int row = row0 + l4 + r;
                size_t co = (size_t)row * 512 + hc;
                float gi = sigf(acc[0][r]);
                float gf = sigf(acc[1][r]);
                float gg = tanh_fast(acc[2][r]);
                float go = sigf(acc[3][r]);
                float cold = (t == 0) ? 0.f : cds[r];
                float cn = gf * cold + gi * gg;
                float hn = go * tanh_fast(cn);
                cds[r] = cn;
                split_store(hn, Hnh, Hnl, co);
            }
        }
        barx(P.xflags, xcd, ++xk);
        {
            const u16* Hnh = P.decHh + (size_t)((t + 1) & 1) * 524288;
            const u16* Hnl = P.decHl + (size_t)((t + 1) & 1) * 524288;
            const int rt = bm & 1, ct = bm >> 1;
            pstage_gemm<2>(sm, 8, xcd * 128 + rt * 64 + wid * 16, ct * 2,
                           Hnh, Hnl, 512, 4096, Hnh, Hnl, 512,
                           P.Wd1, 64, P.b31, nullptr, 1,
                           nullptr, 0, P.H1h, P.H1l, 1024, wid, l, lr, lk8, l4);
        }
        barx(P.xflags, xcd, ++xk);
        {
            const int rt = bm & 1, ct = bm >> 1;
            pstage_gemm<1>(sm, 16, xcd * 128 + rt * 64 + wid * 16, ct,
                           P.H1h, P.H1l, 1024, 4096, P.H1h, P.H1l, 1024,
                           P.Wd2, 32, P.b33, nullptr, 1,
                           nullptr, 0, P.H2h, P.H2l, 512, wid, l, lr, lk8, l4);
        }
        barx(P.xflags, xcd, ++xk);
        if (bm < 2)
            pdirect_gemm<4>(16, xcd * 128 + bm * 64 + wid * 16, 0,
                            P.H2h, P.H2l, 512, P.Wdo, 4, P.b35, 0,
                            P.outY + (size_t)t * 65536, 64,
                            P.Ydh, P.Ydl, 64, l, lr, lk8, l4);
        barx(P.xflags, xcd, ++xk);
    }
}

// ---------------- host ----------------
extern "C" void kernel_launch(void* const* d_in, const int* in_sizes, int n_in,
                              void* d_out, int out_size, void* d_ws, size_t ws_size,
                              hipStream_t stream) {
    (void)in_sizes; (void)n_in; (void)out_size; (void)ws_size;
    auto F = [&](int i) { return (const float*)d_in[i]; };
    const float* x = F(0);
    const float* y = F(1);
    float* out = (float*)d_out;
    char* base = (char*)d_ws;
    const size_t MB = 1ull << 20;
    const size_t KB = 1024;

    AllP P;
    P.gflags = (u32*)base;                       // 32 KB (512 x 64B)
    P.xflags = (u32*)(base + 32 * KB);           // 32 KB
    char* p = base + 64 * KB;
    P.CGF = (float*)p; p += 8 * MB;
    P.encHh = (u16*)p; p += 4 * MB;
    P.encHl = (u16*)p; p += 4 * MB;
    P.decHh = (u16*)p; p += 2 * MB;
    P.decHl = (u16*)p; p += 2 * MB;
    P.HXYh = (u16*)p; p += 2 * MB;
    P.HXYl = (u16*)p; p += 2 * MB;
    P.H1h = (u16*)p; p += 2 * MB;
    P.H1l = (u16*)p; p += 2 * MB;
    P.H2h = (u16*)p; p += 1 * MB;
    P.H2l = (u16*)p; p += 1 * MB;
    P.muh = (u16*)p; p += 256 * KB;
    P.mul2 = (u16*)p; p += 256 * KB;
    P.Ydh = (u16*)p; p += 128 * KB;
    P.Ydl = (u16*)p; p += 128 * KB;
    u16* Xh = (u16*)p; p += 8 * MB;
    u16* Xl = (u16*)p; p += 8 * MB;
    u16* Yh = (u16*)p; p += (size_t)100 * 1024 * 64 * 2;
    u16* Yl = (u16*)p; p += (size_t)100 * 1024 * 64 * 2;
    u16* W0 = (u16*)p;

    size_t wo = 0;
    auto walloc = [&](size_t elems) { u16* q = W0 + wo; wo += elems * 2; return q; };
    u16* WPX0 = walloc((size_t)1024 * 320);
    u16* WPX1 = walloc((size_t)1024 * 320);
    u16* WPE0 = walloc((size_t)1024 * 320);
    u16* WPE1 = walloc((size_t)1024 * 320);
    u16* WPM1 = walloc((size_t)1024 * 1024);
    u16* WPM2 = walloc((size_t)512 * 1024);
    u16* WPMU = walloc((size_t)128 * 512);
    u16* WPLV = walloc((size_t)128 * 512);
    u16* WPCG = walloc((size_t)2048 * 640);
    u16* WPDG = walloc((size_t)2048 * 576);
    u16* WPD1 = walloc((size_t)1024 * 512);
    u16* WPD2 = walloc((size_t)512 * 1024);
    u16* WPDO = walloc((size_t)64 * 512);

    auto prep = [&](const float* s1, int ld1, int k1, const float* s2, int ld2,
                    u16* o, int N, int KT) {
        prep_w<<<(N * KT / 8) / 256, 256, 0, stream>>>(s1, ld1, k1, s2, ld2, o, N / 16);
    };
    prep(F(2), 64, 64, F(3), 256, WPX0, 1024, 320);
    prep(F(6), 64, 64, F(7), 256, WPX1, 1024, 320);
    prep(F(10), 64, 64, F(11), 256, WPE0, 1024, 320);
    prep(F(14), 64, 64, F(15), 256, WPE1, 1024, 320);
    prep(F(18), 1024, 1024, F(18), 1024, WPM1, 1024, 1024);
    prep(F(20), 1024, 1024, F(20), 1024, WPM2, 512, 1024);
    prep(F(22), 512, 512, F(22), 512, WPMU, 128, 512);
    prep(F(24), 512, 512, F(24), 512, WPLV, 128, 512);
    prep(F(26), 704, 640, F(26), 704, WPCG, 2048, 640);
    prep(F(26) + 640, 704, 64, F(27), 512, WPDG, 2048, 576);
    prep(F(30), 512, 512, F(30), 512, WPD1, 1024, 512);
    prep(F(32), 1024, 1024, F(32), 1024, WPD2, 512, 1024);
    prep(F(34), 512, 512, F(34), 512, WPDO, 64, 512);

    prep_act<<<4096, 256, 0, stream>>>(x, Xh, Xl, 64 * 1024 * 64 / 4);
    prep_act<<<6400, 256, 0, stream>>>(y, Yh, Yl, 100 * 1024 * 64 / 4);

    hipMemsetAsync(base, 0, 64 * KB, stream);  // barrier flags only

    P.Xh = Xh; P.Xl = Xl; P.Yh = Yh; P.Yl = Yl;
    const int wi[4] = {2, 6, 10, 14};
    u16* wps[4] = {WPX0, WPX1, WPE0, WPE1};
    for (int s = 0; s < 4; ++s) {
        P.Wenc[s] = wps[s];
        P.ebi[s] = F(wi[s] + 2);
        P.ebh[s] = F(wi[s] + 3);
    }
    P.Wm1 = WPM1; P.Wm2 = WPM2; P.Wmu = WPMU; P.Wlv = WPLV;
    P.Wcg = WPCG; P.Wdg = WPDG; P.Wd1 = WPD1; P.Wd2 = WPD2; P.Wdo = WPDO;
    P.b19 = F(19); P.b21 = F(21); P.b23 = F(23); P.b25 = F(25);
    P.b28 = F(28); P.b29 = F(29); P.b31 = F(31); P.b33 = F(33); P.b35 = F(35);
    P.outY = out;
    P.muF = out + (size_t)100 * 1024 * 64;
    P.lvF = P.muF + (size_t)1024 * 128;

    vae_persist<<<512, 256, 0, stream>>>(P);
}

// Round 16
// 8410.210 us; speedup vs baseline: 1.7565x; 1.0149x over previous
//
#include <hip/hip_runtime.h>

typedef unsigned short u16;
typedef unsigned int u32;
typedef __attribute__((ext_vector_type(8))) short s16x8;
typedef __attribute__((ext_vector_type(4))) float f32x4;

#define MFMA_BF16 __builtin_amdgcn_mfma_f32_16x16x32_bf16
#define SCOPE_AGT __HIP_MEMORY_SCOPE_AGENT

__device__ __forceinline__ float sigf(float x) { return 1.f / (1.f + __expf(-x)); }
__device__ __forceinline__ float tanh_fast(float x) {
    float e = __expf(2.f * x);
    return 1.f - 2.f / (e + 1.f);
}
__device__ __forceinline__ u16 bf16_rn(float x) {
    u32 u = __float_as_uint(x);
    u += 0x7FFFu + ((u >> 16) & 1u);
    return (u16)(u >> 16);
}
__device__ __forceinline__ void split_store(float v, u16* __restrict__ ph,
                                            u16* __restrict__ pl, size_t off) {
    u16 h = bf16_rn(v);
    float hf = __uint_as_float(((u32)h) << 16);
    ph[off] = h;
    pl[off] = bf16_rn(v - hf);
}
__device__ __forceinline__ void mma3(f32x4& acc, s16x8 ah, s16x8 al, s16x8 wh, s16x8 wl) {
    acc = MFMA_BF16(ah, wh, acc, 0, 0, 0);
    acc = MFMA_BF16(al, wh, acc, 0, 0, 0);
    acc = MFMA_BF16(ah, wl, acc, 0, 0, 0);
}
__device__ __forceinline__ void gll16(const u16* g, u16* l) {
    __builtin_amdgcn_global_load_lds(
        (const __attribute__((address_space(1))) u32*)g,
        (__attribute__((address_space(3))) u32*)l, 16, 0, 0);
}

// ---------------- weight prep: fragment blocks, plane-separated ----------------
__global__ __launch_bounds__(256) void prep_w(const float* __restrict__ S1, int ld1, int K1,
                                              const float* __restrict__ S2, int ld2,
                                              u16* __restrict__ out, int NF) {
    int idx = blockIdx.x * 256 + threadIdx.x;
    int l = idx & 63;
    int u = idx >> 6;
    int f = u % NF;
    int s = u / NF;
    int n = f * 16 + (l & 15);
    int kb = s * 32 + ((l >> 4) << 3);
    u16* o = out + (size_t)u * 1024 + l * 8;
#pragma unroll
    for (int j = 0; j < 8; ++j) {
        int k = kb + j;
        float v = (k < K1) ? S1[(size_t)n * ld1 + k] : S2[(size_t)n * ld2 + (k - K1)];
        u16 h = bf16_rn(v);
        float hf = __uint_as_float(((u32)h) << 16);
        o[j] = h;
        o[512 + j] = bf16_rn(v - hf);
    }
}

__global__ __launch_bounds__(256) void prep_act(const float* __restrict__ in,
                                                u16* __restrict__ hi, u16* __restrict__ lo,
                                                int n4) {
    int i = blockIdx.x * 256 + threadIdx.x;
    if (i >= n4) return;
    float4 v = ((const float4*)in)[i];
    float vv[4] = {v.x, v.y, v.z, v.w};
    u16 h[4], lw[4];
#pragma unroll
    for (int j = 0; j < 4; ++j) {
        h[j] = bf16_rn(vv[j]);
        float hf = __uint_as_float(((u32)h[j]) << 16);
        lw[j] = bf16_rn(vv[j] - hf);
    }
    ((ushort4*)hi)[i] = make_ushort4(h[0], h[1], h[2], h[3]);
    ((ushort4*)lo)[i] = make_ushort4(lw[0], lw[1], lw[2], lw[3]);
}

// ---------------- barriers ----------------
__device__ __forceinline__ void barx(u32* __restrict__ flags, int xcd, u32 k) {
    __syncthreads();
    if (threadIdx.x == 0)
        __hip_atomic_store(&flags[blockIdx.x * 16], k, __ATOMIC_RELAXED, SCOPE_AGT);
    if (threadIdx.x < 64) {
        const u32* fp = &flags[(xcd + (int)threadIdx.x * 8) * 16];
        for (;;) {
            u32 v = __hip_atomic_load(fp, __ATOMIC_RELAXED, SCOPE_AGT);
            if (__all((int)(v >= k))) break;
            __builtin_amdgcn_s_sleep(2);
        }
    }
    if (threadIdx.x == 0) asm volatile("buffer_inv" ::: "memory");
    __syncthreads();
}

__device__ __forceinline__ void barg(u32* __restrict__ flags, u32 k) {
    __syncthreads();
    if (threadIdx.x == 0) {
        __builtin_amdgcn_fence(__ATOMIC_RELEASE, "agent");
        __hip_atomic_store(&flags[blockIdx.x * 16], k, __ATOMIC_RELAXED, SCOPE_AGT);
    }
    if (threadIdx.x < 64) {
        for (;;) {
            u32 mn = 0xFFFFFFFFu;
#pragma unroll
            for (int j = 0; j < 8; ++j) {
                u32 v = __hip_atomic_load(&flags[((int)threadIdx.x * 8 + j) * 16],
                                          __ATOMIC_RELAXED, SCOPE_AGT);
                mn = v < mn ? v : mn;
            }
            if (__all((int)(mn >= k))) break;
            __builtin_amdgcn_s_sleep(8);
        }
    }
    if (threadIdx.x == 0) __builtin_amdgcn_fence(__ATOMIC_ACQUIRE, "agent");
    __syncthreads();
}

// ---------------- params ----------------
struct AllP {
    const u16 *Xh, *Xl, *Yh, *Yl;
    const float* ebi[4];
    const float* ebh[4];
    const float *b19, *b21, *b23, *b25, *b28, *b29, *b31, *b33, *b35;
    const u16* Wenc[4];
    const u16 *Wm1, *Wm2, *Wmu, *Wlv, *Wcg, *Wdg, *Wd1, *Wd2, *Wdo;
    u16 *encHh, *encHl, *decHh, *decHl;
    u16 *HXYh, *HXYl, *H1h, *H1l, *H2h, *H2l, *muh, *mul2, *Ydh, *Ydl;
    float* CGF;
    float *outY, *muF, *lvF;
    u32 *gflags, *xflags;
};

// ---------------- staged GEMM, BK=64 substeps (R15) ----------------
template <int CF>
__device__ __forceinline__ void pstage_gemm(
    u16* sm, int nd, int row0, int fbase,
    const u16* __restrict__ A1h, const u16* __restrict__ A1l, int ld1, int K1,
    const u16* __restrict__ A2h, const u16* __restrict__ A2l, int ld2,
    const u16* __restrict__ Wp, int NF,
    const float* __restrict__ b1, const float* __restrict__ b2, int ACT,
    float* __restrict__ outFrag, int fragbase,
    u16* __restrict__ Oh, u16* __restrict__ Ol, int ldop,
    int wid, int l, int lr, int lk8, int l4) {
    const int rowA = row0 + lr;
    constexpr int SLOT = 2 * CF * 1024;

    auto stage = [&](int d, int buf) {
        u16* dst = sm + buf * SLOT;
#pragma unroll
        for (int c = 0; c < CF; ++c) {
            int ch = wid + 4 * c;
            int slice = ch / (2 * CF);
            int rem = ch % (2 * CF);
            int f = rem >> 1, half = rem & 1;
            gll16(Wp + (size_t)((2 * d + slice) * NF + fbase + f) * 1024 + half * 512 + l * 8,
                  dst + slice * CF * 1024 + f * 1024 + half * 512);
        }
    };

    f32x4 acc[CF] = {};
    stage(0, 0);
    __syncthreads();
    for (int d = 0; d < nd; ++d) {
        if (d + 1 < nd) stage(d + 1, (d + 1) & 1);
        const u16* cur = sm + (d & 1) * SLOT;
#pragma unroll
        for (int sl = 0; sl < 2; ++sl) {
            int kb = d * 64 + sl * 32 + lk8;
            const u16* ph = (kb < K1) ? A1h : A2h;
            const u16* pl2 = (kb < K1) ? A1l : A2l;
            size_t off = (kb < K1) ? ((size_t)rowA * ld1 + kb)
                                   : ((size_t)rowA * ld2 + (kb - K1));
            s16x8 ah = *(const s16x8*)(ph + off), al = *(const s16x8*)(pl2 + off);
#pragma unroll
            for (int cf = 0; cf < CF; ++cf) {
                s16x8 wh = *(const s16x8*)(cur + sl * CF * 1024 + cf * 1024 + l * 8);
                s16x8 wl = *(const s16x8*)(cur + sl * CF * 1024 + cf * 1024 + 512 + l * 8);
                mma3(acc[cf], ah, al, wh, wl);
            }
        }
        __syncthreads();
    }
#pragma unroll
    for (int cf = 0; cf < CF; ++cf) {
        int col = (fbase + cf) * 16 + lr;
        float bv = (b1 ? b1[col] : 0.f) + (b2 ? b2[col] : 0.f);
        f32x4 v4;
#pragma unroll
        for (int r = 0; r < 4; ++r) {
            float v = acc[cf][r] + bv;
            if (ACT) v = tanh_fast(v);
            v4[r] = v;
            int row = row0 + l4 + r;
            if (Oh) split_store(v, Oh, Ol, (size_t)row * ldop + col);
        }
        if (outFrag) *(f32x4*)(outFrag + (size_t)(fragbase + cf) * 256 + l * 4) = v4;
    }
}

// ---------------- direct-load GEMM (small weights) ----------------
template <int CF>
__device__ __forceinline__ void pdirect_gemm(
    int ns, int row0, int fbase,
    const u16* __restrict__ A1h, const u16* __restrict__ A1l, int ld1,
    const u16* __restrict__ Wp, int NF,
    const float* __restrict__ b1, int ACT,
    float* __restrict__ outF, int ldo,
    u16* __restrict__ Oh, u16* __restrict__ Ol, int ldop,
    int l, int lr, int lk8, int l4) {
    const s16x8* wp = (const s16x8*)Wp;
    const int rowA = row0 + lr;
    f32x4 acc[CF] = {};
    for (int s = 0; s < ns; ++s) {
        int kb = s * 32 + lk8;
        size_t off = (size_t)rowA * ld1 + kb;
        s16x8 ah = *(const s16x8*)(A1h + off), al = *(const s16x8*)(A1l + off);
#pragma unroll
        for (int cf = 0; cf < CF; ++cf) {
            int fi = s * NF + fbase + cf;
            mma3(acc[cf], ah, al, wp[fi * 128 + l], wp[fi * 128 + 64 + l]);
        }
    }
#pragma unroll
    for (int cf = 0; cf < CF; ++cf) {
        int col = (fbase + cf) * 16 + lr;
        float bv = b1 ? b1[col] : 0.f;
#pragma unroll
        for (int r = 0; r < 4; ++r) {
            float v = acc[cf][r] + bv;
            if (ACT) v = tanh_fast(v);
            int row = row0 + l4 + r;
            if (outF) outF[(size_t)row * ldo + col] = v;
            if (Oh) split_store(v, Oh, Ol, (size_t)row * ldop + col);
        }
    }
}

// ---------------- y = h2 @ Wdo^T + b35 for 64 block rows -> smY planes (+store) ------
__device__ __forceinline__ void ycompute(
    const u16* __restrict__ H2h, const u16* __restrict__ H2l,
    const u16* __restrict__ Wdo, const float* __restrict__ b35,
    u16* __restrict__ smY, float* __restrict__ outYt, int row0g, int storeY,
    int wid, int l, int lr, int lk8, int l4) {
    const s16x8* wp = (const s16x8*)Wdo;
    const int rowA = row0g + wid * 16 + lr;
    f32x4 acc[4] = {};
    for (int s = 0; s < 16; ++s) {
        int kb = s * 32 + lk8;
        size_t off = (size_t)rowA * 512 + kb;
        s16x8 ah = *(const s16x8*)(H2h + off), al = *(const s16x8*)(H2l + off);
#pragma unroll
        for (int cf = 0; cf < 4; ++cf)
            mma3(acc[cf], ah, al, wp[(s * 4 + cf) * 128 + l], wp[(s * 4 + cf) * 128 + 64 + l]);
    }
#pragma unroll
    for (int cf = 0; cf < 4; ++cf) {
        int col = cf * 16 + lr;
        float bv = b35[col];
#pragma unroll
        for (int r = 0; r < 4; ++r) {
            float v = acc[cf][r] + bv;
            int lrow = wid * 16 + l4 + r;
            u16 hh = bf16_rn(v);
            float hf = __uint_as_float(((u32)hh) << 16);
            smY[lrow * 64 + col] = hh;
            smY[4096 + lrow * 64 + col] = bf16_rn(v - hf);
            if (storeY) outYt[(size_t)(row0g + lrow) * 64 + col] = v;
        }
    }
}

// ---------------- the persistent kernel: 512 blocks, 2 per CU ----------------
__global__ __launch_bounds__(256, 2) void vae_persist(AllP P) {
    __shared__ u16 sm[24576];  // 48 KB: [0,16384) W dbuf; [16384,24576) smY planes
    const int tid = threadIdx.x, b = blockIdx.x;
    const int wid = tid >> 6, l = tid & 63;
    const int lr = l & 15, lk8 = (l >> 4) * 8, l4 = (l >> 4) * 4;
    const int xcd = b & 7, bm = b >> 3;
    u32 xk = 0;

    // ================= encoder: XCD-local (unchanged) =================
    {
        const int scan = xcd >> 1;
        const int rowbase = (xcd & 1) * 512;
        const int T = (scan < 2) ? 64 : 100;
        const int rev = scan & 1;
        const u16* Xb = (scan < 2) ? P.Xh : P.Yh;
        const u16* Xlb = (scan < 2) ? P.Xl : P.Yl;
        const s16x8* wp = (const s16x8*)P.Wenc[scan];
        const float* bi = P.ebi[scan];
        const float* bh = P.ebh[scan];
        u16* Hhb = P.encHh + (size_t)scan * 524288;
        u16* Hlb = P.encHl + (size_t)scan * 524288;
        const int rt = bm >> 3, ct = bm & 7;
        const int row0 = rowbase + rt * 64 + wid * 16;
        const int rowA = row0 + lr;
        const int hc0 = ct * 32;
        float cst[2][4] = {};
        float hsr[2][4] = {};

        for (int t = 0; t < T; ++t) {
            const int tt = rev ? (T - 1 - t) : t;
            const u16* xh = Xb + (size_t)tt * 65536;
            const u16* xl = Xlb + (size_t)tt * 65536;
            const u16* Hch = Hhb + (size_t)(t & 1) * 262144;
            const u16* Hcl = Hlb + (size_t)(t & 1) * 262144;
            u16* Hnh = Hhb + (size_t)((t + 1) & 1) * 262144;
            u16* Hnl = Hlb + (size_t)((t + 1) & 1) * 262144;
            f32x4 acc[4][2];
#pragma unroll
            for (int q = 0; q < 4; ++q)
#pragma unroll
                for (int cf = 0; cf < 2; ++cf) {
                    int col = q * 256 + hc0 + cf * 16 + lr;
                    float bv = bi[col] + bh[col];
                    acc[q][cf] = (f32x4){bv, bv, bv, bv};
                }
            const int NS = (t == 0) ? 2 : 10;
            for (int s = 0; s < NS; ++s) {
                int kb = s * 32 + lk8;
                const u16* ph = (kb < 64) ? xh : Hch;
                const u16* pl2 = (kb < 64) ? xl : Hcl;
                size_t off = (kb < 64) ? ((size_t)rowA * 64 + kb)
                                       : ((size_t)rowA * 256 + (kb - 64));
                s16x8 ah = *(const s16x8*)(ph + off), al = *(const s16x8*)(pl2 + off);
#pragma unroll
                for (int q = 0; q < 4; ++q)
#pragma unroll
                    for (int cf = 0; cf < 2; ++cf) {
                        int fi = s * 64 + q * 16 + ct * 2 + cf;
                        mma3(acc[q][cf], ah, al, wp[fi * 128 + l], wp[fi * 128 + 64 + l]);
                    }
            }
#pragma unroll
            for (int cf = 0; cf < 2; ++cf) {
                int hc = hc0 + cf * 16 + lr;
#pragma unroll
                for (int r = 0; r < 4; ++r) {
                    int row = row0 + l4 + r;
                    size_t co = (size_t)row * 256 + hc;
                    float gi = sigf(acc[0][cf][r]);
                    float gf = sigf(acc[1][cf][r]);
                    float gg = tanh_fast(acc[2][cf][r]);
                    float go = sigf(acc[3][cf][r]);
                    float cn = gf * cst[cf][r] + gi * gg;
                    float hn = go * tanh_fast(cn);
                    cst[cf][r] = cn;
                    hsr[cf][r] += hn;
                    split_store(hn, Hnh, Hnl, co);
                }
            }
            barx(P.xflags, xcd, ++xk);
        }
        float sc = (scan < 2) ? (1.f / 64.f) : (1.f / 100.f);
#pragma unroll
        for (int cf = 0; cf < 2; ++cf) {
            int col = scan * 256 + hc0 + cf * 16 + lr;
#pragma unroll
            for (int r = 0; r < 4; ++r) {
                int row = row0 + l4 + r;
                split_store(hsr[cf][r] * sc, P.HXYh, P.HXYl, (size_t)row * 1024 + col);
            }
        }
    }
    barg(P.gflags, 1);  // the ONLY cross-XCD handoff

    // ================= middle (rows xcd*128..+127, XCD-local) =================
    {
        const int rt = bm & 1, ct = bm >> 1;
        pstage_gemm<2>(sm, 16, xcd * 128 + rt * 64 + wid * 16, ct * 2,
                       P.HXYh, P.HXYl, 1024, 4096, P.HXYh, P.HXYl, 1024,
                       P.Wm1, 64, P.b19, nullptr, 1,
                       nullptr, 0, P.H1h, P.H1l, 1024, wid, l, lr, lk8, l4);
    }
    barx(P.xflags, xcd, ++xk);
    {
        const int rt = bm & 1, ct = bm >> 1;
        pstage_gemm<1>(sm, 16, xcd * 128 + rt * 64 + wid * 16, ct,
                       P.H1h, P.H1l, 1024, 4096, P.H1h, P.H1l, 1024,
                       P.Wm2, 32, P.b21, nullptr, 1,
                       nullptr, 0, P.H2h, P.H2l, 512, wid, l, lr, lk8, l4);
    }
    barx(P.xflags, xcd, ++xk);
    {
        if (bm < 16) {
            const int rt = bm & 1, cfi = bm >> 1;
            pdirect_gemm<1>(16, xcd * 128 + rt * 64 + wid * 16, cfi,
                            P.H2h, P.H2l, 512, P.Wmu, 8, P.b23, 0,
                            P.muF, 128, P.muh, P.mul2, 128, l, lr, lk8, l4);
        } else if (bm < 32) {
            const int bm2 = bm - 16;
            const int rt = bm2 & 1, cfi = bm2 >> 1;
            pdirect_gemm<1>(16, xcd * 128 + rt * 64 + wid * 16, cfi,
                            P.H2h, P.H2l, 512, P.Wlv, 8, P.b25, 0,
                            P.lvF, 128, nullptr, nullptr, 0, l, lr, lk8, l4);
        }
    }
    barx(P.xflags, xcd, ++xk);
    {
        const int rt = bm & 1, ct = bm >> 1;
        const int fragbase = (xcd * 8 + rt * 4 + wid) * 128 + ct * 4;
        pstage_gemm<4>(sm, 10, xcd * 128 + rt * 64 + wid * 16, ct * 4,
                       P.HXYh, P.HXYl, 1024, 512, P.muh, P.mul2, 128,
                       P.Wcg, 128, P.b28, P.b29, 0,
                       P.CGF, fragbase, nullptr, nullptr, 0, wid, l, lr, lk8, l4);
    }
    barx(P.xflags, xcd, ++xk);

    // ================= decoder: 3 phases/step (y fused into gates prefix) =============
    float cds[4] = {};
    u16* smY = sm + 16384;
    for (int t = 0; t < 100; ++t) {
        // ---- gates + cell (+ y_{t-1} prefix) ----
        {
            const int rt = bm >> 5, ct = bm & 31;
            const int row0g = xcd * 128 + rt * 64;
            const int row0 = row0g + wid * 16;
            const int rowA = row0 + lr;
            const int RT = xcd * 8 + rt * 4 + wid;
            const u16* Hch = P.decHh + (size_t)(t & 1) * 524288;
            const u16* Hcl = P.decHl + (size_t)(t & 1) * 524288;
            u16* Hnh = P.decHh + (size_t)((t + 1) & 1) * 524288;
            u16* Hnl = P.decHl + (size_t)((t + 1) & 1) * 524288;
            auto stg = [&](int d, int buf) {
#pragma unroll
                for (int c = 0; c < 4; ++c) {
                    int ch = wid + 4 * c;
                    int slice = ch >> 3;
                    int rem = ch & 7;
                    int q = rem >> 1, half = rem & 1;
                    gll16(P.Wdg + (size_t)((2 * d + slice) * 128 + q * 32 + ct) * 1024 +
                              half * 512 + l * 8,
                          sm + buf * 8192 + slice * 4096 + q * 1024 + half * 512);
                }
            };
            f32x4 acc[4];
#pragma unroll
            for (int q = 0; q < 4; ++q)
                acc[q] = *(const f32x4*)(P.CGF +
                         (size_t)(RT * 128 + q * 32 + ct) * 256 + l * 4);
            const int nd = (t == 0) ? 1 : 9;
            stg(0, 0);
            if (t > 0)
                ycompute(P.H2h, P.H2l, P.Wdo, P.b35, smY,
                         P.outY + (size_t)(t - 1) * 65536, row0g, (ct == 0),
                         wid, l, lr, lk8, l4);
            __syncthreads();
            for (int d = 0; d < nd; ++d) {
                if (d + 1 < nd) stg(d + 1, (d + 1) & 1);
                const u16* cur = sm + (d & 1) * 8192;
#pragma unroll
                for (int sl = 0; sl < 2; ++sl) {
                    int kb = d * 64 + sl * 32 + lk8;
                    s16x8 ah, al;
                    if (kb < 64) {
                        if (t == 0) {
                            size_t off = (size_t)63 * 65536 + (size_t)rowA * 64 + kb;
                            ah = *(const s16x8*)(P.Xh + off);
                            al = *(const s16x8*)(P.Xl + off);
                        } else {
                            int lrow = wid * 16 + lr;
                            ah = *(const s16x8*)(smY + lrow * 64 + kb);
                            al = *(const s16x8*)(smY + 4096 + lrow * 64 + kb);
                        }
                    } else {
                        size_t off = (size_t)rowA * 512 + (kb - 64);
                        ah = *(const s16x8*)(Hch + off);
                        al = *(const s16x8*)(Hcl + off);
                    }
#pragma unroll
                    for (int q = 0; q < 4; ++q) {
                        s16x8 wh = *(const s16x8*)(cur + sl * 4096 + q * 1024 + l * 8);
                        s16x8 wl = *(const s16x8*)(cur + sl * 4096 + q * 1024 + 512 + l * 8);
                        mma3(acc[q], ah, al, wh, wl);
                    }
                }
                __syncthreads();
            }
            const int hc = ct * 16 + lr;
#pragma unroll
            for (int r = 0; r < 4; ++r) {
                int row = row0 + l4 + r;
                size_t co = (size_t)row * 512 + hc;
                float gi = sigf(acc[0][r]);
                float gf = sigf(acc[1][r]);
                float gg = tanh_fast(acc[2][r]);
                float go = sigf(acc[3][r]);
                float cold = (t == 0) ? 0.f : cds[r];
                float cn = gf * cold + gi * gg;
                float hn = go * tanh_fast(cn);
                cds[r] = cn;
                split_store(hn, Hnh, Hnl, co);
            }
        }
        barx(P.xflags, xcd, ++xk);
        {
            const u16* Hnh = P.decHh + (size_t)((t + 1) & 1) * 524288;
            const u16* Hnl = P.decHl + (size_t)((t + 1) & 1) * 524288;
            const int rt = bm & 1, ct = bm >> 1;
            pstage_gemm<2>(sm, 8, xcd * 128 + rt * 64 + wid * 16, ct * 2,
                           Hnh, Hnl, 512, 4096, Hnh, Hnl, 512,
                           P.Wd1, 64, P.b31, nullptr, 1,
                           nullptr, 0, P.H1h, P.H1l, 1024, wid, l, lr, lk8, l4);
        }
        barx(P.xflags, xcd, ++xk);
        {
            const int rt = bm & 1, ct = bm >> 1;
            pstage_gemm<1>(sm, 16, xcd * 128 + rt * 64 + wid * 16, ct,
                           P.H1h, P.H1l, 1024, 4096, P.H1h, P.H1l, 1024,
                           P.Wd2, 32, P.b33, nullptr, 1,
                           nullptr, 0, P.H2h, P.H2l, 512, wid, l, lr, lk8, l4);
        }
        barx(P.xflags, xcd, ++xk);
    }
    // tail: y for t=99 (H2 planes final, visible after last barx)
    if ((bm & 31) == 0) {
        const int rt = bm >> 5;
        ycompute(P.H2h, P.H2l, P.Wdo, P.b35, smY,
                 P.outY + (size_t)99 * 65536, xcd * 128 + rt * 64, 1,
                 wid, l, lr, lk8, l4);
    }
}

// ---------------- host ----------------
extern "C" void kernel_launch(void* const* d_in, const int* in_sizes, int n_in,
                              void* d_out, int out_size, void* d_ws, size_t ws_size,
                              hipStream_t stream) {
    (void)in_sizes; (void)n_in; (void)out_size; (void)ws_size;
    auto F = [&](int i) { return (const float*)d_in[i]; };
    const float* x = F(0);
    const float* y = F(1);
    float* out = (float*)d_out;
    char* base = (char*)d_ws;
    const size_t MB = 1ull << 20;
    const size_t KB = 1024;

    AllP P;
    P.gflags = (u32*)base;                       // 32 KB
    P.xflags = (u32*)(base + 32 * KB);           // 32 KB
    char* p = base + 64 * KB;
    P.CGF = (float*)p; p += 8 * MB;
    P.encHh = (u16*)p; p += 4 * MB;
    P.encHl = (u16*)p; p += 4 * MB;
    P.decHh = (u16*)p; p += 2 * MB;
    P.decHl = (u16*)p; p += 2 * MB;
    P.HXYh = (u16*)p; p += 2 * MB;
    P.HXYl = (u16*)p; p += 2 * MB;
    P.H1h = (u16*)p; p += 2 * MB;
    P.H1l = (u16*)p; p += 2 * MB;
    P.H2h = (u16*)p; p += 1 * MB;
    P.H2l = (u16*)p; p += 1 * MB;
    P.muh = (u16*)p; p += 256 * KB;
    P.mul2 = (u16*)p; p += 256 * KB;
    P.Ydh = (u16*)p; p += 128 * KB;
    P.Ydl = (u16*)p; p += 128 * KB;
    u16* Xh = (u16*)p; p += 8 * MB;
    u16* Xl = (u16*)p; p += 8 * MB;
    u16* Yh = (u16*)p; p += (size_t)100 * 1024 * 64 * 2;
    u16* Yl = (u16*)p; p += (size_t)100 * 1024 * 64 * 2;
    u16* W0 = (u16*)p;

    size_t wo = 0;
    auto walloc = [&](size_t elems) { u16* q = W0 + wo; wo += elems * 2; return q; };
    u16* WPX0 = walloc((size_t)1024 * 320);
    u16* WPX1 = walloc((size_t)1024 * 320);
    u16* WPE0 = walloc((size_t)1024 * 320);
    u16* WPE1 = walloc((size_t)1024 * 320);
    u16* WPM1 = walloc((size_t)1024 * 1024);
    u16* WPM2 = walloc((size_t)512 * 1024);
    u16* WPMU = walloc((size_t)128 * 512);
    u16* WPLV = walloc((size_t)128 * 512);
    u16* WPCG = walloc((size_t)2048 * 640);
    u16* WPDG = walloc((size_t)2048 * 576);
    u16* WPD1 = walloc((size_t)1024 * 512);
    u16* WPD2 = walloc((size_t)512 * 1024);
    u16* WPDO = walloc((size_t)64 * 512);

    auto prep = [&](const float* s1, int ld1, int k1, const float* s2, int ld2,
                    u16* o, int N, int KT) {
        prep_w<<<(N * KT / 8) / 256, 256, 0, stream>>>(s1, ld1, k1, s2, ld2, o, N / 16);
    };
    prep(F(2), 64, 64, F(3), 256, WPX0, 1024, 320);
    prep(F(6), 64, 64, F(7), 256, WPX1, 1024, 320);
    prep(F(10), 64, 64, F(11), 256, WPE0, 1024, 320);
    prep(F(14), 64, 64, F(15), 256, WPE1, 1024, 320);
    prep(F(18), 1024, 1024, F(18), 1024, WPM1, 1024, 1024);
    prep(F(20), 1024, 1024, F(20), 1024, WPM2, 512, 1024);
    prep(F(22), 512, 512, F(22), 512, WPMU, 128, 512);
    prep(F(24), 512, 512, F(24), 512, WPLV, 128, 512);
    prep(F(26), 704, 640, F(26), 704, WPCG, 2048, 640);
    prep(F(26) + 640, 704, 64, F(27), 512, WPDG, 2048, 576);
    prep(F(30), 512, 512, F(30), 512, WPD1, 1024, 512);
    prep(F(32), 1024, 1024, F(32), 1024, WPD2, 512, 1024);
    prep(F(34), 512, 512, F(34), 512, WPDO, 64, 512);

    prep_act<<<4096, 256, 0, stream>>>(x, Xh, Xl, 64 * 1024 * 64 / 4);
    prep_act<<<6400, 256, 0, stream>>>(y, Yh, Yl, 100 * 1024 * 64 / 4);

    hipMemsetAsync(base, 0, 64 * KB, stream);  // barrier flags only

    P.Xh = Xh; P.Xl = Xl; P.Yh = Yh; P.Yl = Yl;
    const int wi[4] = {2, 6, 10, 14};
    u16* wps[4] = {WPX0, WPX1, WPE0, WPE1};
    for (int s = 0; s < 4; ++s) {
        P.Wenc[s] = wps[s];
        P.ebi[s] = F(wi[s] + 2);
        P.ebh[s] = F(wi[s] + 3);
    }
    P.Wm1 = WPM1; P.Wm2 = WPM2; P.Wmu = WPMU; P.Wlv = WPLV;
    P.Wcg = WPCG; P.Wdg = WPDG; P.Wd1 = WPD1; P.Wd2 = WPD2; P.Wdo = WPDO;
    P.b19 = F(19); P.b21 = F(21); P.b23 = F(23); P.b25 = F(25);
    P.b28 = F(28); P.b29 = F(29); P.b31 = F(31); P.b33 = F(33); P.b35 = F(35);
    P.outY = out;
    P.muF = out + (size_t)100 * 1024 * 64;
    P.lvF = P.muF + (size_t)1024 * 128;

    vae_persist<<<512, 256, 0, stream>>>(P);
}

// Round 17
// 8329.954 us; speedup vs baseline: 1.7735x; 1.0096x over previous
//
#include <hip/hip_runtime.h>

typedef unsigned short u16;
typedef unsigned int u32;
typedef __attribute__((ext_vector_type(8))) short s16x8;
typedef __attribute__((ext_vector_type(4))) float f32x4;

#define MFMA_BF16 __builtin_amdgcn_mfma_f32_16x16x32_bf16
#define SCOPE_AGT __HIP_MEMORY_SCOPE_AGENT

__device__ __forceinline__ float sigf(float x) { return 1.f / (1.f + __expf(-x)); }
__device__ __forceinline__ float tanh_fast(float x) {
    float e = __expf(2.f * x);
    return 1.f - 2.f / (e + 1.f);
}
__device__ __forceinline__ u16 bf16_rn(float x) {
    u32 u = __float_as_uint(x);
    u += 0x7FFFu + ((u >> 16) & 1u);
    return (u16)(u >> 16);
}
__device__ __forceinline__ void split_store(float v, u16* __restrict__ ph,
                                            u16* __restrict__ pl, size_t off) {
    u16 h = bf16_rn(v);
    float hf = __uint_as_float(((u32)h) << 16);
    ph[off] = h;
    pl[off] = bf16_rn(v - hf);
}
__device__ __forceinline__ void mma3(f32x4& acc, s16x8 ah, s16x8 al, s16x8 wh, s16x8 wl) {
    acc = MFMA_BF16(ah, wh, acc, 0, 0, 0);
    acc = MFMA_BF16(al, wh, acc, 0, 0, 0);
    acc = MFMA_BF16(ah, wl, acc, 0, 0, 0);
}
__device__ __forceinline__ void gll16(const u16* g, u16* l) {
    __builtin_amdgcn_global_load_lds(
        (const __attribute__((address_space(1))) u32*)g,
        (__attribute__((address_space(3))) u32*)l, 16, 0, 0);
}

// ---------------- weight prep: fragment blocks; WPL=2 hi/lo, WPL=1 hi only ---------
__global__ __launch_bounds__(256) void prep_w(const float* __restrict__ S1, int ld1, int K1,
                                              const float* __restrict__ S2, int ld2,
                                              u16* __restrict__ out, int NF, int WPL) {
    int idx = blockIdx.x * 256 + threadIdx.x;
    int l = idx & 63;
    int u = idx >> 6;
    int f = u % NF;
    int s = u / NF;
    int n = f * 16 + (l & 15);
    int kb = s * 32 + ((l >> 4) << 3);
    u16* o = out + (size_t)u * (WPL * 512) + l * 8;
#pragma unroll
    for (int j = 0; j < 8; ++j) {
        int k = kb + j;
        float v = (k < K1) ? S1[(size_t)n * ld1 + k] : S2[(size_t)n * ld2 + (k - K1)];
        u16 h = bf16_rn(v);
        o[j] = h;
        if (WPL == 2) {
            float hf = __uint_as_float(((u32)h) << 16);
            o[512 + j] = bf16_rn(v - hf);
        }
    }
}

__global__ __launch_bounds__(256) void prep_act(const float* __restrict__ in,
                                                u16* __restrict__ hi, u16* __restrict__ lo,
                                                int n4) {
    int i = blockIdx.x * 256 + threadIdx.x;
    if (i >= n4) return;
    float4 v = ((const float4*)in)[i];
    float vv[4] = {v.x, v.y, v.z, v.w};
    u16 h[4], lw[4];
#pragma unroll
    for (int j = 0; j < 4; ++j) {
        h[j] = bf16_rn(vv[j]);
        float hf = __uint_as_float(((u32)h[j]) << 16);
        lw[j] = bf16_rn(vv[j] - hf);
    }
    ((ushort4*)hi)[i] = make_ushort4(h[0], h[1], h[2], h[3]);
    ((ushort4*)lo)[i] = make_ushort4(lw[0], lw[1], lw[2], lw[3]);
}

// ---------------- barriers ----------------
__device__ __forceinline__ void barx(u32* __restrict__ flags, int xcd, u32 k) {
    __syncthreads();
    if (threadIdx.x == 0)
        __hip_atomic_store(&flags[blockIdx.x * 16], k, __ATOMIC_RELAXED, SCOPE_AGT);
    if (threadIdx.x < 64) {
        const u32* fp = &flags[(xcd + (int)threadIdx.x * 8) * 16];
        for (;;) {
            u32 v = __hip_atomic_load(fp, __ATOMIC_RELAXED, SCOPE_AGT);
            if (__all((int)(v >= k))) break;
            __builtin_amdgcn_s_sleep(2);
        }
    }
    if (threadIdx.x == 0) asm volatile("buffer_inv" ::: "memory");
    __syncthreads();
}

__device__ __forceinline__ void barg(u32* __restrict__ flags, u32 k) {
    __syncthreads();
    if (threadIdx.x == 0) {
        __builtin_amdgcn_fence(__ATOMIC_RELEASE, "agent");
        __hip_atomic_store(&flags[blockIdx.x * 16], k, __ATOMIC_RELAXED, SCOPE_AGT);
    }
    if (threadIdx.x < 64) {
        for (;;) {
            u32 mn = 0xFFFFFFFFu;
#pragma unroll
            for (int j = 0; j < 8; ++j) {
                u32 v = __hip_atomic_load(&flags[((int)threadIdx.x * 8 + j) * 16],
                                          __ATOMIC_RELAXED, SCOPE_AGT);
                mn = v < mn ? v : mn;
            }
            if (__all((int)(mn >= k))) break;
            __builtin_amdgcn_s_sleep(8);
        }
    }
    if (threadIdx.x == 0) __builtin_amdgcn_fence(__ATOMIC_ACQUIRE, "agent");
    __syncthreads();
}

// ---------------- params ----------------
struct AllP {
    const u16 *Xh, *Xl, *Yh, *Yl;
    const float* ebi[4];
    const float* ebh[4];
    const float *b19, *b21, *b23, *b25, *b28, *b29, *b31, *b33, *b35;
    const u16* Wenc[4];
    const u16 *Wm1, *Wm2, *Wmu, *Wlv, *Wcg, *Wdg, *Wd1, *Wd2, *Wdo;
    u16 *encHh, *encHl, *decHh, *decHl;
    u16 *HXYh, *HXYl, *H1h, *H1l, *H2h, *H2l, *muh, *mul2, *Ydh, *Ydl;
    float* CGF;
    float *outY, *muF, *lvF;
    u32 *gflags, *xflags;
};

// ---------------- staged GEMM, BK=64 substeps; WPL = weight planes (1|2) ------------
template <int CF, int WPL>
__device__ __forceinline__ void pstage_gemm(
    u16* sm, int nd, int row0, int fbase,
    const u16* __restrict__ A1h, const u16* __restrict__ A1l, int ld1, int K1,
    const u16* __restrict__ A2h, const u16* __restrict__ A2l, int ld2,
    const u16* __restrict__ Wp, int NF,
    const float* __restrict__ b1, const float* __restrict__ b2, int ACT,
    float* __restrict__ outFrag, int fragbase,
    u16* __restrict__ Oh, u16* __restrict__ Ol, int ldop,
    int wid, int l, int lr, int lk8, int l4) {
    const int rowA = row0 + lr;
    constexpr int FB = WPL * 512;          // u16 per frag-block
    constexpr int SLOT = 2 * CF * FB;      // u16 per dbuf
    constexpr int NCH = 2 * CF * WPL;      // 512-u16 chunks per stage
    constexpr int NIT = (NCH + 3) / 4;

    auto stage = [&](int d, int buf) {
        u16* dst = sm + buf * SLOT;
#pragma unroll
        for (int c = 0; c < NIT; ++c) {
            int ch = wid + 4 * c;
            if ((NCH & 3) && ch >= NCH) continue;
            int slice = ch / (CF * WPL);
            int rem = ch % (CF * WPL);
            int f = rem / WPL, half = rem % WPL;
            gll16(Wp + (size_t)((2 * d + slice) * NF + fbase + f) * FB + half * 512 + l * 8,
                  dst + slice * CF * FB + f * FB + half * 512);
        }
    };

    f32x4 acc[CF] = {};
    stage(0, 0);
    __syncthreads();
    for (int d = 0; d < nd; ++d) {
        if (d + 1 < nd) stage(d + 1, (d + 1) & 1);
        const u16* cur = sm + (d & 1) * SLOT;
#pragma unroll
        for (int sl = 0; sl < 2; ++sl) {
            int kb = d * 64 + sl * 32 + lk8;
            const u16* ph = (kb < K1) ? A1h : A2h;
            const u16* pl2 = (kb < K1) ? A1l : A2l;
            size_t off = (kb < K1) ? ((size_t)rowA * ld1 + kb)
                                   : ((size_t)rowA * ld2 + (kb - K1));
            s16x8 ah = *(const s16x8*)(ph + off), al = *(const s16x8*)(pl2 + off);
#pragma unroll
            for (int cf = 0; cf < CF; ++cf) {
                s16x8 wh = *(const s16x8*)(cur + sl * CF * FB + cf * FB + l * 8);
                if (WPL == 2) {
                    s16x8 wl = *(const s16x8*)(cur + sl * CF * FB + cf * FB + 512 + l * 8);
                    mma3(acc[cf], ah, al, wh, wl);
                } else {
                    acc[cf] = MFMA_BF16(ah, wh, acc[cf], 0, 0, 0);
                    acc[cf] = MFMA_BF16(al, wh, acc[cf], 0, 0, 0);
                }
            }
        }
        __syncthreads();
    }
#pragma unroll
    for (int cf = 0; cf < CF; ++cf) {
        int col = (fbase + cf) * 16 + lr;
        float bv = (b1 ? b1[col] : 0.f) + (b2 ? b2[col] : 0.f);
        f32x4 v4;
#pragma unroll
        for (int r = 0; r < 4; ++r) {
            float v = acc[cf][r] + bv;
            if (ACT) v = tanh_fast(v);
            v4[r] = v;
            int row = row0 + l4 + r;
            if (Oh) split_store(v, Oh, Ol, (size_t)row * ldop + col);
        }
        if (outFrag) *(f32x4*)(outFrag + (size_t)(fragbase + cf) * 256 + l * 4) = v4;
    }
}

// ---------------- direct-load GEMM (small hi/lo weights) ----------------
template <int CF>
__device__ __forceinline__ void pdirect_gemm(
    int ns, int row0, int fbase,
    const u16* __restrict__ A1h, const u16* __restrict__ A1l, int ld1,
    const u16* __restrict__ Wp, int NF,
    const float* __restrict__ b1, int ACT,
    float* __restrict__ outF, int ldo,
    u16* __restrict__ Oh, u16* __restrict__ Ol, int ldop,
    int l, int lr, int lk8, int l4) {
    const s16x8* wp = (const s16x8*)Wp;
    const int rowA = row0 + lr;
    f32x4 acc[CF] = {};
    for (int s = 0; s < ns; ++s) {
        int kb = s * 32 + lk8;
        size_t off = (size_t)rowA * ld1 + kb;
        s16x8 ah = *(const s16x8*)(A1h + off), al = *(const s16x8*)(A1l + off);
#pragma unroll
        for (int cf = 0; cf < CF; ++cf) {
            int fi = s * NF + fbase + cf;
            mma3(acc[cf], ah, al, wp[fi * 128 + l], wp[fi * 128 + 64 + l]);
        }
    }
#pragma unroll
    for (int cf = 0; cf < CF; ++cf) {
        int col = (fbase + cf) * 16 + lr;
        float bv = b1 ? b1[col] : 0.f;
#pragma unroll
        for (int r = 0; r < 4; ++r) {
            float v = acc[cf][r] + bv;
            if (ACT) v = tanh_fast(v);
            int row = row0 + l4 + r;
            if (outF) outF[(size_t)row * ldo + col] = v;
            if (Oh) split_store(v, Oh, Ol, (size_t)row * ldop + col);
        }
    }
}

// ---------------- y = h2 @ Wdo^T + b35 -> smY planes (stride 72, conflict-free) -----
__device__ __forceinline__ void ycompute(
    const u16* __restrict__ H2h, const u16* __restrict__ H2l,
    const u16* __restrict__ Wdo, const float* __restrict__ b35,
    u16* __restrict__ smY, float* __restrict__ outYt, int row0g, int storeY,
    int wid, int l, int lr, int lk8, int l4) {
    const s16x8* wp = (const s16x8*)Wdo;
    const int rowA = row0g + wid * 16 + lr;
    f32x4 acc[4] = {};
    for (int s = 0; s < 16; ++s) {
        int kb = s * 32 + lk8;
        size_t off = (size_t)rowA * 512 + kb;
        s16x8 ah = *(const s16x8*)(H2h + off), al = *(const s16x8*)(H2l + off);
#pragma unroll
        for (int cf = 0; cf < 4; ++cf)
            mma3(acc[cf], ah, al, wp[(s * 4 + cf) * 128 + l], wp[(s * 4 + cf) * 128 + 64 + l]);
    }
#pragma unroll
    for (int cf = 0; cf < 4; ++cf) {
        int col = cf * 16 + lr;
        float bv = b35[col];
#pragma unroll
        for (int r = 0; r < 4; ++r) {
            float v = acc[cf][r] + bv;
            int lrow = wid * 16 + l4 + r;
            u16 hh = bf16_rn(v);
            float hf = __uint_as_float(((u32)hh) << 16);
            smY[lrow * 72 + col] = hh;
            smY[4608 + lrow * 72 + col] = bf16_rn(v - hf);
            if (storeY) outYt[(size_t)(row0g + lrow) * 64 + col] = v;
        }
    }
}

// ---------------- the persistent kernel: 512 blocks, 2 per CU ----------------
__global__ __launch_bounds__(256, 2) void vae_persist(AllP P) {
    __shared__ u16 sm[25600];  // [0,16384) W dbuf; [16384,25600) smY (64x72 x2 planes)
    const int tid = threadIdx.x, b = blockIdx.x;
    const int wid = tid >> 6, l = tid & 63;
    const int lr = l & 15, lk8 = (l >> 4) * 8, l4 = (l >> 4) * 4;
    const int xcd = b & 7, bm = b >> 3;
    u32 xk = 0;

    // ================= encoder: XCD-local (unchanged) =================
    {
        const int scan = xcd >> 1;
        const int rowbase = (xcd & 1) * 512;
        const int T = (scan < 2) ? 64 : 100;
        const int rev = scan & 1;
        const u16* Xb = (scan < 2) ? P.Xh : P.Yh;
        const u16* Xlb = (scan < 2) ? P.Xl : P.Yl;
        const s16x8* wp = (const s16x8*)P.Wenc[scan];
        const float* bi = P.ebi[scan];
        const float* bh = P.ebh[scan];
        u16* Hhb = P.encHh + (size_t)scan * 524288;
        u16* Hlb = P.encHl + (size_t)scan * 524288;
        const int rt = bm >> 3, ct = bm & 7;
        const int row0 = rowbase + rt * 64 + wid * 16;
        const int rowA = row0 + lr;
        const int hc0 = ct * 32;
        float cst[2][4] = {};
        float hsr[2][4] = {};

        for (int t = 0; t < T; ++t) {
            const int tt = rev ? (T - 1 - t) : t;
            const u16* xh = Xb + (size_t)tt * 65536;
            const u16* xl = Xlb + (size_t)tt * 65536;
            const u16* Hch = Hhb + (size_t)(t & 1) * 262144;
            const u16* Hcl = Hlb + (size_t)(t & 1) * 262144;
            u16* Hnh = Hhb + (size_t)((t + 1) & 1) * 262144;
            u16* Hnl = Hlb + (size_t)((t + 1) & 1) * 262144;
            f32x4 acc[4][2];
#pragma unroll
            for (int q = 0; q < 4; ++q)
#pragma unroll
                for (int cf = 0; cf < 2; ++cf) {
                    int col = q * 256 + hc0 + cf * 16 + lr;
                    float bv = bi[col] + bh[col];
                    acc[q][cf] = (f32x4){bv, bv, bv, bv};
                }
            const int NS = (t == 0) ? 2 : 10;
            for (int s = 0; s < NS; ++s) {
                int kb = s * 32 + lk8;
                const u16* ph = (kb < 64) ? xh : Hch;
                const u16* pl2 = (kb < 64) ? xl : Hcl;
                size_t off = (kb < 64) ? ((size_t)rowA * 64 + kb)
                                       : ((size_t)rowA * 256 + (kb - 64));
                s16x8 ah = *(const s16x8*)(ph + off), al = *(const s16x8*)(pl2 + off);
#pragma unroll
                for (int q = 0; q < 4; ++q)
#pragma unroll
                    for (int cf = 0; cf < 2; ++cf) {
                        int fi = s * 64 + q * 16 + ct * 2 + cf;
                        mma3(acc[q][cf], ah, al, wp[fi * 128 + l], wp[fi * 128 + 64 + l]);
                    }
            }
#pragma unroll
            for (int cf = 0; cf < 2; ++cf) {
                int hc = hc0 + cf * 16 + lr;
#pragma unroll
                for (int r = 0; r < 4; ++r) {
                    int row = row0 + l4 + r;
                    size_t co = (size_t)row * 256 + hc;
                    float gi = sigf(acc[0][cf][r]);
                    float gf = sigf(acc[1][cf][r]);
                    float gg = tanh_fast(acc[2][cf][r]);
                    float go = sigf(acc[3][cf][r]);
                    float cn = gf * cst[cf][r] + gi * gg;
                    float hn = go * tanh_fast(cn);
                    cst[cf][r] = cn;
                    hsr[cf][r] += hn;
                    split_store(hn, Hnh, Hnl, co);
                }
            }
            barx(P.xflags, xcd, ++xk);
        }
        float sc = (scan < 2) ? (1.f / 64.f) : (1.f / 100.f);
#pragma unroll
        for (int cf = 0; cf < 2; ++cf) {
            int col = scan * 256 + hc0 + cf * 16 + lr;
#pragma unroll
            for (int r = 0; r < 4; ++r) {
                int row = row0 + l4 + r;
                split_store(hsr[cf][r] * sc, P.HXYh, P.HXYl, (size_t)row * 1024 + col);
            }
        }
    }
    barg(P.gflags, 1);  // the ONLY cross-XCD handoff

    // ================= middle (rows xcd*128..+127, XCD-local) =================
    {
        const int rt = bm & 1, ct = bm >> 1;
        pstage_gemm<2, 1>(sm, 16, xcd * 128 + rt * 64 + wid * 16, ct * 2,
                          P.HXYh, P.HXYl, 1024, 4096, P.HXYh, P.HXYl, 1024,
                          P.Wm1, 64, P.b19, nullptr, 1,
                          nullptr, 0, P.H1h, P.H1l, 1024, wid, l, lr, lk8, l4);
    }
    barx(P.xflags, xcd, ++xk);
    {
        const int rt = bm & 1, ct = bm >> 1;
        pstage_gemm<1, 1>(sm, 16, xcd * 128 + rt * 64 + wid * 16, ct,
                          P.H1h, P.H1l, 1024, 4096, P.H1h, P.H1l, 1024,
                          P.Wm2, 32, P.b21, nullptr, 1,
                          nullptr, 0, P.H2h, P.H2l, 512, wid, l, lr, lk8, l4);
    }
    barx(P.xflags, xcd, ++xk);
    {
        if (bm < 16) {
            const int rt = bm & 1, cfi = bm >> 1;
            pdirect_gemm<1>(16, xcd * 128 + rt * 64 + wid * 16, cfi,
                            P.H2h, P.H2l, 512, P.Wmu, 8, P.b23, 0,
                            P.muF, 128, P.muh, P.mul2, 128, l, lr, lk8, l4);
        } else if (bm < 32) {
            const int bm2 = bm - 16;
            const int rt = bm2 & 1, cfi = bm2 >> 1;
            pdirect_gemm<1>(16, xcd * 128 + rt * 64 + wid * 16, cfi,
                            P.H2h, P.H2l, 512, P.Wlv, 8, P.b25, 0,
                            P.lvF, 128, nullptr, nullptr, 0, l, lr, lk8, l4);
        }
    }
    barx(P.xflags, xcd, ++xk);
    {
        const int rt = bm & 1, ct = bm >> 1;
        const int fragbase = (xcd * 8 + rt * 4 + wid) * 128 + ct * 4;
        pstage_gemm<4, 2>(sm, 10, xcd * 128 + rt * 64 + wid * 16, ct * 4,
                          P.HXYh, P.HXYl, 1024, 512, P.muh, P.mul2, 128,
                          P.Wcg, 128, P.b28, P.b29, 0,
                          P.CGF, fragbase, nullptr, nullptr, 0, wid, l, lr, lk8, l4);
    }
    barx(P.xflags, xcd, ++xk);

    // ================= decoder: 3 phases/step (y fused into gates prefix) =============
    float cds[4] = {};
    u16* smY = sm + 16384;
    for (int t = 0; t < 100; ++t) {
        // ---- gates + cell (+ y_{t-1} prefix) ----
        {
            const int rt = bm >> 5, ct = bm & 31;
            const int row0g = xcd * 128 + rt * 64;
            const int row0 = row0g + wid * 16;
            const int rowA = row0 + lr;
            const int RT = xcd * 8 + rt * 4 + wid;
            const u16* Hch = P.decHh + (size_t)(t & 1) * 524288;
            const u16* Hcl = P.decHl + (size_t)(t & 1) * 524288;
            u16* Hnh = P.decHh + (size_t)((t + 1) & 1) * 524288;
            u16* Hnl = P.decHl + (size_t)((t + 1) & 1) * 524288;
            auto stg = [&](int d, int buf) {
#pragma unroll
                for (int c = 0; c < 4; ++c) {
                    int ch = wid + 4 * c;
                    int slice = ch >> 3;
                    int rem = ch & 7;
                    int q = rem >> 1, half = rem & 1;
                    gll16(P.Wdg + (size_t)((2 * d + slice) * 128 + q * 32 + ct) * 1024 +
                              half * 512 + l * 8,
                          sm + buf * 8192 + slice * 4096 + q * 1024 + half * 512);
                }
            };
            f32x4 acc[4];
#pragma unroll
            for (int q = 0; q < 4; ++q)
                acc[q] = *(const f32x4*)(P.CGF +
                         (size_t)(RT * 128 + q * 32 + ct) * 256 + l * 4);
            const int nd = (t == 0) ? 1 : 9;
            stg(0, 0);
            if (t > 0)
                ycompute(P.H2h, P.H2l, P.Wdo, P.b35, smY,
                         P.outY + (size_t)(t - 1) * 65536, row0g, (ct == 0),
                         wid, l, lr, lk8, l4);
            __syncthreads();
            for (int d = 0; d < nd; ++d) {
                if (d + 1 < nd) stg(d + 1, (d + 1) & 1);
                const u16* cur = sm + (d & 1) * 8192;
#pragma unroll
                for (int sl = 0; sl < 2; ++sl) {
                    int kb = d * 64 + sl * 32 + lk8;
                    s16x8 ah, al;
                    if (kb < 64) {
                        if (t == 0) {
                            size_t off = (size_t)63 * 65536 + (size_t)rowA * 64 + kb;
                            ah = *(const s16x8*)(P.Xh + off);
                            al = *(const s16x8*)(P.Xl + off);
                        } else {
                            int lrow = wid * 16 + lr;
                            ah = *(const s16x8*)(smY + lrow * 72 + kb);
                            al = *(const s16x8*)(smY + 4608 + lrow * 72 + kb);
                        }
                    } else {
                        size_t off = (size_t)rowA * 512 + (kb - 64);
                        ah = *(const s16x8*)(Hch + off);
                        al = *(const s16x8*)(Hcl + off);
                    }
#pragma unroll
                    for (int q = 0; q < 4; ++q) {
                        s16x8 wh = *(const s16x8*)(cur + sl * 4096 + q * 1024 + l * 8);
                        s16x8 wl = *(const s16x8*)(cur + sl * 4096 + q * 1024 + 512 + l * 8);
                        mma3(acc[q], ah, al, wh, wl);
                    }
                }
                __syncthreads();
            }
            const int hc = ct * 16 + lr;
#pragma unroll
            for (int r = 0; r < 4; ++r) {
                int row = row0 + l4 + r;
                size_t co = (size_t)row * 512 + hc;
                float gi = sigf(acc[0][r]);
                float gf = sigf(acc[1][r]);
                float gg = tanh_fast(acc[2][r]);
                float go = sigf(acc[3][r]);
                float cold = (t == 0) ? 0.f : cds[r];
                float cn = gf * cold + gi * gg;
                float hn = go * tanh_fast(cn);
                cds[r] = cn;
                split_store(hn, Hnh, Hnl, co);
            }
        }
        barx(P.xflags, xcd, ++xk);
        {
            const u16* Hnh = P.decHh + (size_t)((t + 1) & 1) * 524288;
            const u16* Hnl = P.decHl + (size_t)((t + 1) & 1) * 524288;
            const int rt = bm & 1, ct = bm >> 1;
            pstage_gemm<2, 1>(sm, 8, xcd * 128 + rt * 64 + wid * 16, ct * 2,
                              Hnh, Hnl, 512, 4096, Hnh, Hnl, 512,
                              P.Wd1, 64, P.b31, nullptr, 1,
                              nullptr, 0, P.H1h, P.H1l, 1024, wid, l, lr, lk8, l4);
        }
        barx(P.xflags, xcd, ++xk);
        {
            const int rt = bm & 1, ct = bm >> 1;
            pstage_gemm<1, 1>(sm, 16, xcd * 128 + rt * 64 + wid * 16, ct,
                              P.H1h, P.H1l, 1024, 4096, P.H1h, P.H1l, 1024,
                              P.Wd2, 32, P.b33, nullptr, 1,
                              nullptr, 0, P.H2h, P.H2l, 512, wid, l, lr, lk8, l4);
        }
        barx(P.xflags, xcd, ++xk);
    }
    // tail: y for t=99
    if ((bm & 31) == 0) {
        const int rt = bm >> 5;
        ycompute(P.H2h, P.H2l, P.Wdo, P.b35, smY,
                 P.outY + (size_t)99 * 65536, xcd * 128 + rt * 64, 1,
                 wid, l, lr, lk8, l4);
    }
}

// ---------------- host ----------------
extern "C" void kernel_launch(void* const* d_in, const int* in_sizes, int n_in,
                              void* d_out, int out_size, void* d_ws, size_t ws_size,
                              hipStream_t stream) {
    (void)in_sizes; (void)n_in; (void)out_size; (void)ws_size;
    auto F = [&](int i) { return (const float*)d_in[i]; };
    const float* x = F(0);
    const float* y = F(1);
    float* out = (float*)d_out;
    char* base = (char*)d_ws;
    const size_t MB = 1ull << 20;
    const size_t KB = 1024;

    AllP P;
    P.gflags = (u32*)base;                       // 32 KB
    P.xflags = (u32*)(base + 32 * KB);           // 32 KB
    char* p = base + 64 * KB;
    P.CGF = (float*)p; p += 8 * MB;
    P.encHh = (u16*)p; p += 4 * MB;
    P.encHl = (u16*)p; p += 4 * MB;
    P.decHh = (u16*)p; p += 2 * MB;
    P.decHl = (u16*)p; p += 2 * MB;
    P.HXYh = (u16*)p; p += 2 * MB;
    P.HXYl = (u16*)p; p += 2 * MB;
    P.H1h = (u16*)p; p += 2 * MB;
    P.H1l = (u16*)p; p += 2 * MB;
    P.H2h = (u16*)p; p += 1 * MB;
    P.H2l = (u16*)p; p += 1 * MB;
    P.muh = (u16*)p; p += 256 * KB;
    P.mul2 = (u16*)p; p += 256 * KB;
    P.Ydh = (u16*)p; p += 128 * KB;
    P.Ydl = (u16*)p; p += 128 * KB;
    u16* Xh = (u16*)p; p += 8 * MB;
    u16* Xl = (u16*)p; p += 8 * MB;
    u16* Yh = (u16*)p; p += (size_t)100 * 1024 * 64 * 2;
    u16* Yl = (u16*)p; p += (size_t)100 * 1024 * 64 * 2;
    u16* W0 = (u16*)p;

    size_t wo = 0;
    auto walloc2 = [&](size_t elems) { u16* q = W0 + wo; wo += elems * 2; return q; };
    auto walloc1 = [&](size_t elems) { u16* q = W0 + wo; wo += elems; return q; };
    u16* WPX0 = walloc2((size_t)1024 * 320);
    u16* WPX1 = walloc2((size_t)1024 * 320);
    u16* WPE0 = walloc2((size_t)1024 * 320);
    u16* WPE1 = walloc2((size_t)1024 * 320);
    u16* WPM1 = walloc1((size_t)1024 * 1024);
    u16* WPM2 = walloc1((size_t)512 * 1024);
    u16* WPMU = walloc2((size_t)128 * 512);
    u16* WPLV = walloc2((size_t)128 * 512);
    u16* WPCG = walloc2((size_t)2048 * 640);
    u16* WPDG = walloc2((size_t)2048 * 576);
    u16* WPD1 = walloc1((size_t)1024 * 512);
    u16* WPD2 = walloc1((size_t)512 * 1024);
    u16* WPDO = walloc2((size_t)64 * 512);

    auto prep = [&](const float* s1, int ld1, int k1, const float* s2, int ld2,
                    u16* o, int N, int KT, int wpl) {
        prep_w<<<(N * KT / 8) / 256, 256, 0, stream>>>(s1, ld1, k1, s2, ld2, o, N / 16, wpl);
    };
    prep(F(2), 64, 64, F(3), 256, WPX0, 1024, 320, 2);
    prep(F(6), 64, 64, F(7), 256, WPX1, 1024, 320, 2);
    prep(F(10), 64, 64, F(11), 256, WPE0, 1024, 320, 2);
    prep(F(14), 64, 64, F(15), 256, WPE1, 1024, 320, 2);
    prep(F(18), 1024, 1024, F(18), 1024, WPM1, 1024, 1024, 1);
    prep(F(20), 1024, 1024, F(20), 1024, WPM2, 512, 1024, 1);
    prep(F(22), 512, 512, F(22), 512, WPMU, 128, 512, 2);
    prep(F(24), 512, 512, F(24), 512, WPLV, 128, 512, 2);
    prep(F(26), 704, 640, F(26), 704, WPCG, 2048, 640, 2);
    prep(F(26) + 640, 704, 64, F(27), 512, WPDG, 2048, 576, 2);
    prep(F(30), 512, 512, F(30), 512, WPD1, 1024, 512, 1);
    prep(F(32), 1024, 1024, F(32), 1024, WPD2, 512, 1024, 1);
    prep(F(34), 512, 512, F(34), 512, WPDO, 64, 512, 2);

    prep_act<<<4096, 256, 0, stream>>>(x, Xh, Xl, 64 * 1024 * 64 / 4);
    prep_act<<<6400, 256, 0, stream>>>(y, Yh, Yl, 100 * 1024 * 64 / 4);

    hipMemsetAsync(base, 0, 64 * KB, stream);  // barrier flags only

    P.Xh = Xh; P.Xl = Xl; P.Yh = Yh; P.Yl = Yl;
    const int wi[4] = {2, 6, 10, 14};
    u16* wps[4] = {WPX0, WPX1, WPE0, WPE1};
    for (int s = 0; s < 4; ++s) {
        P.Wenc[s] = wps[s];
        P.ebi[s] = F(wi[s] + 2);
        P.ebh[s] = F(wi[s] + 3);
    }
    P.Wm1 = WPM1; P.Wm2 = WPM2; P.Wmu = WPMU; P.Wlv = WPLV;
    P.Wcg = WPCG; P.Wdg = WPDG; P.Wd1 = WPD1; P.Wd2 = WPD2; P.Wdo = WPDO;
    P.b19 = F(19); P.b21 = F(21); P.b23 = F(23); P.b25 = F(25);
    P.b28 = F(28); P.b29 = F(29); P.b31 = F(31); P.b33 = F(33); P.b35 = F(35);
    P.outY = out;
    P.muF = out + (size_t)100 * 1024 * 64;
    P.lvF = P.muF + (size_t)1024 * 128;

    vae_persist<<<512, 256, 0, stream>>>(P);
}